// Round 1
// baseline (3849.240 us; speedup 1.0000x reference)
//
#include <hip/hip_runtime.h>
#include <hip/hip_bf16.h>
#include <math.h>

// MP Attention: b=2, n=2048, dim=1024, h=16, d=64.
// Pipeline:
//  1. norm_rows: wn = w / (max(||row||,eps) * sqrt(1024))   (w_qkv, w_out)
//  2. gemm_nt:   qkv[4096][3072] = x[4096][1024] @ wn_qkv^T
//  3. attn:      flash-style online softmax; pixel-norm applied in-kernel
//                (q: /max(||q||,eps)  — the *8 and *1/8 cancel;
//                 k,v: *8/max(||.||,eps)); mem_kv = masked first tile (4 rows)
//  4. gemm_nt:   out = attn_out @ wn_out^T, fused residual
//                (acc*0.7 + x*0.3) * (1/sqrt(0.58))

#define EPSN 1e-4f

__global__ __launch_bounds__(256) void norm_rows(const float* __restrict__ w,
                                                 float* __restrict__ wn, int cols) {
    __shared__ float red[256];
    int r = blockIdx.x;
    const float* row = w + (size_t)r * cols;
    float ss = 0.0f;
    for (int c = threadIdx.x; c < cols; c += 256) { float v = row[c]; ss += v * v; }
    red[threadIdx.x] = ss;
    __syncthreads();
    for (int s = 128; s > 0; s >>= 1) {
        if (threadIdx.x < s) red[threadIdx.x] += red[threadIdx.x + s];
        __syncthreads();
    }
    float f = 1.0f / (fmaxf(sqrtf(red[0]), EPSN) * 32.0f);  // sqrt(1024)=32
    for (int c = threadIdx.x; c < cols; c += 256) wn[(size_t)r * cols + c] = row[c] * f;
}

// C[M][N] = A[M][K] @ B[N][K]^T ; optional fused MP-residual epilogue.
__global__ __launch_bounds__(256) void gemm_nt(const float* __restrict__ A,
                                               const float* __restrict__ B,
                                               float* __restrict__ C,
                                               int M, int N, int K,
                                               const float* __restrict__ resid) {
    __shared__ float As[16][68];  // [k][m], pad 4 for b128 alignment
    __shared__ float Bs[16][68];  // [k][n]
    int tx = threadIdx.x;         // 0..15
    int ty = threadIdx.y;         // 0..15
    int tid = ty * 16 + tx;
    int m0 = blockIdx.y * 64;
    int n0 = blockIdx.x * 64;
    float acc[4][4];
    for (int i = 0; i < 4; i++)
        for (int j = 0; j < 4; j++) acc[i][j] = 0.0f;

    for (int kk = 0; kk < K; kk += 16) {
        for (int e = 0; e < 4; e++) {
            int p = e * 256 + tid;        // 0..1023
            int m = p >> 4;               // 0..63
            int k = p & 15;
            As[k][m] = A[(size_t)(m0 + m) * K + kk + k];
            Bs[k][m] = B[(size_t)(n0 + m) * K + kk + k];
        }
        __syncthreads();
        for (int k = 0; k < 16; k++) {
            float a[4], b[4];
            for (int i = 0; i < 4; i++) a[i] = As[k][ty * 4 + i];
            for (int j = 0; j < 4; j++) b[j] = Bs[k][tx * 4 + j];
            for (int i = 0; i < 4; i++)
                for (int j = 0; j < 4; j++) acc[i][j] += a[i] * b[j];
        }
        __syncthreads();
    }
    for (int i = 0; i < 4; i++) {
        for (int j = 0; j < 4; j++) {
            size_t idx = (size_t)(m0 + ty * 4 + i) * N + (n0 + tx * 4 + j);
            float v = acc[i][j];
            if (resid) v = (v * 0.7f + resid[idx] * 0.3f) * 1.3130643285972254f; // 1/sqrt(0.58)
            C[idx] = v;
        }
    }
}

__global__ __launch_bounds__(256) void attn_kernel(const float* __restrict__ qkv,
                                                   const float* __restrict__ memkv,
                                                   float* __restrict__ out) {
    const int n = 2048;
    int bh = blockIdx.x;           // b*16 + h
    int bb = bh >> 4, h = bh & 15;
    int q0 = blockIdx.y * 64;
    int tid = threadIdx.x;

    __shared__ float qs[64][68];
    __shared__ float ks[32][68];
    __shared__ float vs[32][68];
    __shared__ float ps[64][33];
    __shared__ float mrow[64], lrow[64], arow[64];

    // ---- load q tile (coalesced: one row per 64 lanes) ----
    for (int e = 0; e < 16; e++) {
        int p = e * 256 + tid;
        int r = p >> 6, c = p & 63;
        qs[r][c] = qkv[((size_t)(bb * n + q0 + r)) * 3072 + h * 64 + c];
    }
    __syncthreads();
    // q pixel-norm: pn(q)*scale = q / max(||q||, eps)   (×8 and ×1/8 cancel)
    if (tid < 64) {
        float ss = 0.0f;
        for (int c = 0; c < 64; c++) { float v = qs[tid][c]; ss += v * v; }
        float f = 1.0f / fmaxf(sqrtf(ss), EPSN);
        for (int c = 0; c < 64; c++) qs[tid][c] *= f;
        mrow[tid] = -1e30f;
        lrow[tid] = 0.0f;
    }

    float acc[16];
    for (int d = 0; d < 16; d++) acc[d] = 0.0f;
    const int qi = tid >> 2;          // row owned in softmax/PV phases
    const int part = tid & 3;
    const int dbase = part * 16;

    const int ntiles = 1 + n / 32;    // tile 0 = 4 mem-kv rows, then 64 tiles of 32
    for (int tile = 0; tile < ntiles; tile++) {
        __syncthreads();   // protect ks/vs/ps from previous iteration's readers
        int nk;
        if (tile == 0) {
            nk = 4;
            int r = tid >> 6, c = tid & 63;   // 256 threads = 4 rows x 64 cols
            ks[r][c] = memkv[((0 * 16 + h) * 4 + r) * 64 + c];
            vs[r][c] = memkv[((1 * 16 + h) * 4 + r) * 64 + c];
        } else {
            nk = 32;
            int k0 = (tile - 1) * 32;
            for (int e = 0; e < 8; e++) {
                int p = e * 256 + tid;
                int r = p >> 6, c = p & 63;
                size_t base = ((size_t)(bb * n + k0 + r)) * 3072 + h * 64 + c;
                ks[r][c] = qkv[base + 1024];
                vs[r][c] = qkv[base + 2048];
            }
        }
        __syncthreads();
        // k,v pixel-norm: *8 / max(||.||, eps)
        if (tid < nk) {
            float ss = 0.0f;
            for (int c = 0; c < 64; c++) { float v = ks[tid][c]; ss += v * v; }
            float f = 8.0f / fmaxf(sqrtf(ss), EPSN);
            for (int c = 0; c < 64; c++) ks[tid][c] *= f;
        } else if (tid >= 64 && tid < 64 + nk) {
            int r = tid - 64;
            float ss = 0.0f;
            for (int c = 0; c < 64; c++) { float v = vs[r][c]; ss += v * v; }
            float f = 8.0f / fmaxf(sqrtf(ss), EPSN);
            for (int c = 0; c < 64; c++) vs[r][c] *= f;
        }
        __syncthreads();
        // ---- scores: thread (sq,sj) covers rows sq*8..sq*8+7 vs key sj ----
        {
            int sj = tid & 31, sq = tid >> 5;
            for (int it = 0; it < 8; it++) {
                int r = sq * 8 + it;
                float s = 0.0f;
                for (int c = 0; c < 64; c++) s += qs[r][c] * ks[sj][c];
                ps[r][sj] = (sj < nk) ? s : -1e30f;
            }
        }
        __syncthreads();
        // ---- online softmax: 4 threads per row (lanes 4qi..4qi+3) ----
        {
            float mx = -1e30f;
            for (int j = part * 8; j < part * 8 + 8; j++) mx = fmaxf(mx, ps[qi][j]);
            mx = fmaxf(mx, __shfl_xor(mx, 1));
            mx = fmaxf(mx, __shfl_xor(mx, 2));
            float mold = mrow[qi];
            float mnew = fmaxf(mold, mx);
            float sum = 0.0f;
            for (int j = part * 8; j < part * 8 + 8; j++) {
                float pv = __expf(ps[qi][j] - mnew);   // masked -1e30 -> 0
                ps[qi][j] = pv;
                sum += pv;
            }
            sum += __shfl_xor(sum, 1);
            sum += __shfl_xor(sum, 2);
            if (part == 0) {
                float alpha = __expf(mold - mnew);
                mrow[qi] = mnew;
                lrow[qi] = lrow[qi] * alpha + sum;
                arow[qi] = alpha;
            }
        }
        __syncthreads();
        // ---- PV accumulate: thread owns (qi, 16 d-cols) ----
        {
            float alpha = arow[qi];
            for (int d = 0; d < 16; d++) acc[d] *= alpha;
            for (int j = 0; j < nk; j++) {     // j<nk: rows >= nk hold stale data
                float pv = ps[qi][j];
                for (int d = 0; d < 16; d++) acc[d] += pv * vs[j][dbase + d];
            }
        }
    }
    __syncthreads();
    float inv_l = 1.0f / lrow[qi];
    size_t token = (size_t)(bb * n + q0 + qi);
    for (int d = 0; d < 16; d++)
        out[token * 1024 + h * 64 + dbase + d] = acc[d] * inv_l;
}

extern "C" void kernel_launch(void* const* d_in, const int* in_sizes, int n_in,
                              void* d_out, int out_size, void* d_ws, size_t ws_size,
                              hipStream_t stream) {
    const float* x      = (const float*)d_in[0];   // [2,2048,1024]
    const float* w_qkv  = (const float*)d_in[1];   // [3072,1024]
    const float* w_out  = (const float*)d_in[2];   // [1024,1024]
    const float* mem_kv = (const float*)d_in[3];   // [2,16,4,64]
    float* out = (float*)d_out;                    // [2,2048,1024]

    float* ws = (float*)d_ws;
    float* wn_qkv   = ws;                  // 3072*1024
    float* wn_out   = ws + 3145728;        // 1024*1024
    float* qkv      = ws + 4194304;        // 4096*3072
    float* attn_out = ws + 16777216;       // 4096*1024
    // total: 20971520 floats = 80 MB

    norm_rows<<<3072, 256, 0, stream>>>(w_qkv, wn_qkv, 1024);
    norm_rows<<<1024, 256, 0, stream>>>(w_out, wn_out, 1024);

    // qkv = x @ wn_qkv^T : M=4096, N=3072, K=1024
    gemm_nt<<<dim3(3072 / 64, 4096 / 64), dim3(16, 16), 0, stream>>>(
        x, wn_qkv, qkv, 4096, 3072, 1024, nullptr);

    attn_kernel<<<dim3(32, 32), 256, 0, stream>>>(qkv, mem_kv, attn_out);

    // out = attn_out @ wn_out^T with fused MP residual: M=4096, N=1024, K=1024
    gemm_nt<<<dim3(1024 / 64, 4096 / 64), dim3(16, 16), 0, stream>>>(
        attn_out, wn_out, out, 4096, 1024, 1024, x);
}

// Round 2
// 771.939 us; speedup vs baseline: 4.9865x; 4.9865x over previous
//
#include <hip/hip_runtime.h>
#include <hip/hip_bf16.h>
#include <math.h>

// MP Attention: b=2, n=2048, dim=1024, h=16, d=64.
//  1. norm_rows: wn = w / (max(||row||,eps) * 32)
//  2. gemm_nt:   qkv[4096][3072] = x @ wn_qkv^T            (fp32 vector, next round: MFMA)
//  3. attn_mfma: flash attention, bf16 MFMA 16x16x32, pixel-norm fused at stage time
//  4. gemm_nt:   out = attn_out @ wn_out^T + fused MP residual

#define EPSN 1e-4f
#define LDH 72   // LDS leading dim in shorts: 144 B rows -> 16B-aligned, rows spread 2-way on banks

typedef __attribute__((ext_vector_type(8))) short short8;
typedef __attribute__((ext_vector_type(4))) float floatx4;

__device__ __forceinline__ short f2bf(float f) {
    union { float f; unsigned u; } c{f};
    unsigned r = (c.u + 0x7FFF + ((c.u >> 16) & 1)) >> 16;  // round-to-nearest-even
    return (short)r;
}

__global__ __launch_bounds__(256) void norm_rows(const float* __restrict__ w,
                                                 float* __restrict__ wn, int cols) {
    __shared__ float red[256];
    int r = blockIdx.x;
    const float* row = w + (size_t)r * cols;
    float ss = 0.0f;
    for (int c = threadIdx.x; c < cols; c += 256) { float v = row[c]; ss += v * v; }
    red[threadIdx.x] = ss;
    __syncthreads();
    for (int s = 128; s > 0; s >>= 1) {
        if (threadIdx.x < s) red[threadIdx.x] += red[threadIdx.x + s];
        __syncthreads();
    }
    float f = 1.0f / (fmaxf(sqrtf(red[0]), EPSN) * 32.0f);
    for (int c = threadIdx.x; c < cols; c += 256) wn[(size_t)r * cols + c] = row[c] * f;
}

// C[M][N] = A[M][K] @ B[N][K]^T ; optional fused MP-residual epilogue.
__global__ __launch_bounds__(256) void gemm_nt(const float* __restrict__ A,
                                               const float* __restrict__ B,
                                               float* __restrict__ C,
                                               int M, int N, int K,
                                               const float* __restrict__ resid) {
    __shared__ float As[16][68];
    __shared__ float Bs[16][68];
    int tx = threadIdx.x, ty = threadIdx.y;
    int tid = ty * 16 + tx;
    int m0 = blockIdx.y * 64, n0 = blockIdx.x * 64;
    float acc[4][4];
    for (int i = 0; i < 4; i++)
        for (int j = 0; j < 4; j++) acc[i][j] = 0.0f;

    for (int kk = 0; kk < K; kk += 16) {
        for (int e = 0; e < 4; e++) {
            int p = e * 256 + tid;
            int m = p >> 4, k = p & 15;
            As[k][m] = A[(size_t)(m0 + m) * K + kk + k];
            Bs[k][m] = B[(size_t)(n0 + m) * K + kk + k];
        }
        __syncthreads();
        for (int k = 0; k < 16; k++) {
            float a[4], b[4];
            for (int i = 0; i < 4; i++) a[i] = As[k][ty * 4 + i];
            for (int j = 0; j < 4; j++) b[j] = Bs[k][tx * 4 + j];
            for (int i = 0; i < 4; i++)
                for (int j = 0; j < 4; j++) acc[i][j] += a[i] * b[j];
        }
        __syncthreads();
    }
    for (int i = 0; i < 4; i++)
        for (int j = 0; j < 4; j++) {
            size_t idx = (size_t)(m0 + ty * 4 + i) * N + (n0 + tx * 4 + j);
            float v = acc[i][j];
            if (resid) v = (v * 0.7f + resid[idx] * 0.3f) * 1.3130643285972254f;
            C[idx] = v;
        }
}

// Flash attention with bf16 MFMA.
// Block: 256 thr = 4 waves; 64 q rows per block (16 per wave). K-tile = 64 keys.
// Tile 0 = mem_kv (4 valid keys, rest masked/zeroed); tiles 1..32 = the 2048 keys.
__global__ __launch_bounds__(256) void attn_mfma(const float* __restrict__ qkv,
                                                 const float* __restrict__ memkv,
                                                 float* __restrict__ out) {
    const int n = 2048;
    const int bh = blockIdx.x;
    const int bb = bh >> 4, h = bh & 15;
    const int q0 = blockIdx.y * 64;
    const int tid = threadIdx.x;
    const int wave = tid >> 6;
    const int lane = tid & 63;
    const int l16 = lane & 15;
    const int quad = lane >> 4;

    __shared__ __align__(16) short Qs[64 * LDH];
    __shared__ __align__(16) short Ks[64 * LDH];
    __shared__ __align__(16) short Vt[64 * LDH];     // transposed: Vt[d][key]
    __shared__ __align__(16) short Ps[4][16 * LDH];  // per-wave P buffer (C-layout -> A-layout)

    // ---- stage Q, pixel-norm fused: q / max(||q||,eps)  (x8 from pn, /8 from scale cancel)
    {
        const int r = tid >> 2, part = tid & 3;
        const float* src = qkv + ((size_t)(bb * n + q0 + r)) * 3072 + h * 64 + part * 16;
        float v[16]; float ss = 0.f;
        #pragma unroll
        for (int i = 0; i < 16; i += 4) {
            float4 f = *(const float4*)(src + i);
            v[i] = f.x; v[i+1] = f.y; v[i+2] = f.z; v[i+3] = f.w;
            ss += f.x*f.x + f.y*f.y + f.z*f.z + f.w*f.w;
        }
        ss += __shfl_xor(ss, 1); ss += __shfl_xor(ss, 2);
        const float fn = 1.0f / fmaxf(sqrtf(ss), EPSN);
        #pragma unroll
        for (int i = 0; i < 16; i++) Qs[r * LDH + part * 16 + i] = f2bf(v[i] * fn);
    }
    __syncthreads();

    // A-fragments of Q held in registers for all 33 tiles (rows wave*16 + l16)
    short8 aQ0, aQ1;
    {
        const short* p = &Qs[(wave * 16 + l16) * LDH + quad * 8];
        aQ0 = *(const short8*)p;
        aQ1 = *(const short8*)(p + 32);
    }

    floatx4 O[4];
    #pragma unroll
    for (int t = 0; t < 4; t++) O[t] = (floatx4){0.f, 0.f, 0.f, 0.f};
    float mrow[4], lrow[4];
    #pragma unroll
    for (int i = 0; i < 4; i++) { mrow[i] = -1e30f; lrow[i] = 0.f; }

    for (int tile = 0; tile < 33; tile++) {
        __syncthreads();  // all waves done reading previous Ks/Vt
        // ---- stage K,V tile with pixel-norm (8/||row||); V transposed into Vt
        {
            const int r = tid >> 2, part = tid & 3;
            float vk[16], vv[16]; float ssk = 0.f, ssv = 0.f;
            if (tile == 0) {
                if (r < 4) {
                    const float* pk = memkv + (size_t)(h * 4 + r) * 64 + part * 16;
                    const float* pv = memkv + (size_t)((16 + h) * 4 + r) * 64 + part * 16;
                    #pragma unroll
                    for (int i = 0; i < 16; i += 4) {
                        float4 a = *(const float4*)(pk + i);
                        float4 b = *(const float4*)(pv + i);
                        vk[i]=a.x; vk[i+1]=a.y; vk[i+2]=a.z; vk[i+3]=a.w;
                        vv[i]=b.x; vv[i+1]=b.y; vv[i+2]=b.z; vv[i+3]=b.w;
                        ssk += a.x*a.x + a.y*a.y + a.z*a.z + a.w*a.w;
                        ssv += b.x*b.x + b.y*b.y + b.z*b.z + b.w*b.w;
                    }
                } else {
                    #pragma unroll
                    for (int i = 0; i < 16; i++) { vk[i] = 0.f; vv[i] = 0.f; }
                }
            } else {
                const size_t base = ((size_t)(bb * n + (tile - 1) * 64 + r)) * 3072 + h * 64 + part * 16;
                #pragma unroll
                for (int i = 0; i < 16; i += 4) {
                    float4 a = *(const float4*)(qkv + base + 1024 + i);
                    float4 b = *(const float4*)(qkv + base + 2048 + i);
                    vk[i]=a.x; vk[i+1]=a.y; vk[i+2]=a.z; vk[i+3]=a.w;
                    vv[i]=b.x; vv[i+1]=b.y; vv[i+2]=b.z; vv[i+3]=b.w;
                    ssk += a.x*a.x + a.y*a.y + a.z*a.z + a.w*a.w;
                    ssv += b.x*b.x + b.y*b.y + b.z*b.z + b.w*b.w;
                }
            }
            ssk += __shfl_xor(ssk, 1); ssk += __shfl_xor(ssk, 2);
            ssv += __shfl_xor(ssv, 1); ssv += __shfl_xor(ssv, 2);
            const float fk = 8.0f / fmaxf(sqrtf(ssk), EPSN);
            const float fv = 8.0f / fmaxf(sqrtf(ssv), EPSN);
            #pragma unroll
            for (int i = 0; i < 16; i++) {
                Ks[r * LDH + part * 16 + i] = f2bf(vk[i] * fk);
                Vt[(part * 16 + i) * LDH + r] = f2bf(vv[i] * fv);
            }
        }
        __syncthreads();

        // ---- scores S = Q·K^T  (C-layout: col(key)=l16+16t, row(q)=quad*4+i)
        floatx4 S[4];
        #pragma unroll
        for (int t = 0; t < 4; t++) {
            const short* pb = &Ks[(t * 16 + l16) * LDH + quad * 8];
            short8 b0 = *(const short8*)pb;
            short8 b1 = *(const short8*)(pb + 32);
            floatx4 s = (floatx4){0.f, 0.f, 0.f, 0.f};
            s = __builtin_amdgcn_mfma_f32_16x16x32_bf16(aQ0, b0, s, 0, 0, 0);
            s = __builtin_amdgcn_mfma_f32_16x16x32_bf16(aQ1, b1, s, 0, 0, 0);
            S[t] = s;
        }
        if (tile == 0) {   // only first 4 mem-kv keys valid
            #pragma unroll
            for (int t = 0; t < 4; t++)
                if (t * 16 + l16 >= 4) { S[t][0] = S[t][1] = S[t][2] = S[t][3] = -1e30f; }
        }
        // ---- online softmax: row stats across the 16-lane column groups
        float alpha[4];
        #pragma unroll
        for (int i = 0; i < 4; i++) {
            float m = fmaxf(fmaxf(S[0][i], S[1][i]), fmaxf(S[2][i], S[3][i]));
            m = fmaxf(m, __shfl_xor(m, 1));
            m = fmaxf(m, __shfl_xor(m, 2));
            m = fmaxf(m, __shfl_xor(m, 4));
            m = fmaxf(m, __shfl_xor(m, 8));
            const float mnew = fmaxf(mrow[i], m);
            alpha[i] = __expf(mrow[i] - mnew);
            mrow[i] = mnew;
        }
        #pragma unroll
        for (int t = 0; t < 4; t++) {
            #pragma unroll
            for (int i = 0; i < 4; i++) S[t][i] = __expf(S[t][i] - mrow[i]);
        }
        #pragma unroll
        for (int i = 0; i < 4; i++) {
            float s = S[0][i] + S[1][i] + S[2][i] + S[3][i];
            s += __shfl_xor(s, 1); s += __shfl_xor(s, 2);
            s += __shfl_xor(s, 4); s += __shfl_xor(s, 8);
            lrow[i] = lrow[i] * alpha[i] + s;
        }
        // ---- rescale O, spill P (C-layout -> LDS), reload as A-fragments
        short* pp = Ps[wave];
        #pragma unroll
        for (int t = 0; t < 4; t++) {
            #pragma unroll
            for (int i = 0; i < 4; i++) {
                O[t][i] *= alpha[i];
                pp[(quad * 4 + i) * LDH + t * 16 + l16] = f2bf(S[t][i]);
            }
        }
        short8 aP0, aP1;
        {
            const short* pa = &pp[l16 * LDH + quad * 8];
            aP0 = *(const short8*)pa;
            aP1 = *(const short8*)(pa + 32);
        }
        // ---- O += P·V   (B-frags contiguous from transposed Vt)
        #pragma unroll
        for (int t = 0; t < 4; t++) {
            const short* pv2 = &Vt[(t * 16 + l16) * LDH + quad * 8];
            short8 b0 = *(const short8*)pv2;
            short8 b1 = *(const short8*)(pv2 + 32);
            O[t] = __builtin_amdgcn_mfma_f32_16x16x32_bf16(aP0, b0, O[t], 0, 0, 0);
            O[t] = __builtin_amdgcn_mfma_f32_16x16x32_bf16(aP1, b1, O[t], 0, 0, 0);
        }
    }

    // ---- epilogue: O / l, write fp32 [b,n,h*d]
    #pragma unroll
    for (int i = 0; i < 4; i++) {
        const float inv = 1.0f / lrow[i];
        const int qrow = q0 + wave * 16 + quad * 4 + i;
        const size_t base = ((size_t)(bb * n + qrow)) * 1024 + h * 64 + l16;
        #pragma unroll
        for (int t = 0; t < 4; t++) out[base + t * 16] = O[t][i] * inv;
    }
}

extern "C" void kernel_launch(void* const* d_in, const int* in_sizes, int n_in,
                              void* d_out, int out_size, void* d_ws, size_t ws_size,
                              hipStream_t stream) {
    const float* x      = (const float*)d_in[0];   // [2,2048,1024]
    const float* w_qkv  = (const float*)d_in[1];   // [3072,1024]
    const float* w_out  = (const float*)d_in[2];   // [1024,1024]
    const float* mem_kv = (const float*)d_in[3];   // [2,16,4,64]
    float* out = (float*)d_out;                    // [2,2048,1024]

    float* ws = (float*)d_ws;
    float* wn_qkv   = ws;                  // 3072*1024
    float* wn_out   = ws + 3145728;        // 1024*1024
    float* qkv      = ws + 4194304;        // 4096*3072
    float* attn_out = ws + 16777216;       // 4096*1024

    norm_rows<<<3072, 256, 0, stream>>>(w_qkv, wn_qkv, 1024);
    norm_rows<<<1024, 256, 0, stream>>>(w_out, wn_out, 1024);

    gemm_nt<<<dim3(3072 / 64, 4096 / 64), dim3(16, 16), 0, stream>>>(
        x, wn_qkv, qkv, 4096, 3072, 1024, nullptr);

    attn_mfma<<<dim3(32, 32), 256, 0, stream>>>(qkv, mem_kv, attn_out);

    gemm_nt<<<dim3(1024 / 64, 4096 / 64), dim3(16, 16), 0, stream>>>(
        attn_out, wn_out, out, 4096, 1024, 1024, x);
}

// Round 3
// 374.339 us; speedup vs baseline: 10.2828x; 2.0621x over previous
//
#include <hip/hip_runtime.h>
#include <hip/hip_bf16.h>
#include <math.h>

// MP Attention: b=2, n=2048, dim=1024, h=16, d=64.
//  0. cast_bf16:  xb = bf16(x)
//  1. norm_rows:  wn = bf16( w / (max(||row||,eps) * 32) )
//  2. gemm_mfma:  qkv[4096][3072] (fp32) = xb @ wn_qkv^T      (bf16 MFMA, m97 structure)
//  3. attn_mfma:  flash attention, bf16 MFMA, pixel-norm fused; writes bf16
//  4. gemm_mfma:  out = attn_b @ wn_out^T + fused MP residual (fp32 out)

#define EPSN 1e-4f
#define LDH 72

typedef __attribute__((ext_vector_type(8))) short short8;
typedef __attribute__((ext_vector_type(4))) short short4v;
typedef __attribute__((ext_vector_type(4))) float floatx4;

typedef __attribute__((address_space(1))) const void g_void;
typedef __attribute__((address_space(3))) void lds_void;

__device__ __forceinline__ void async16(void* lds, const void* g) {
    // per-lane global addr; LDS dest = wave-uniform base + lane*16
    __builtin_amdgcn_global_load_lds((g_void*)g, (lds_void*)lds, 16, 0, 0);
}

__device__ __forceinline__ short f2bf(float f) {
    union { float f; unsigned u; } c{f};
    unsigned r = (c.u + 0x7FFF + ((c.u >> 16) & 1)) >> 16;
    return (short)r;
}

__global__ __launch_bounds__(256) void cast_bf16(const float* __restrict__ in,
                                                 short* __restrict__ out) {
    int i = (blockIdx.x * 256 + threadIdx.x) * 4;
    float4 v = *(const float4*)(in + i);
    short4v s = {f2bf(v.x), f2bf(v.y), f2bf(v.z), f2bf(v.w)};
    *(short4v*)(out + i) = s;
}

__global__ __launch_bounds__(256) void norm_rows(const float* __restrict__ w,
                                                 short* __restrict__ wn, int cols) {
    __shared__ float red[256];
    int r = blockIdx.x;
    const float* row = w + (size_t)r * cols;
    float ss = 0.0f;
    for (int c = threadIdx.x; c < cols; c += 256) { float v = row[c]; ss += v * v; }
    red[threadIdx.x] = ss;
    __syncthreads();
    for (int s = 128; s > 0; s >>= 1) {
        if (threadIdx.x < s) red[threadIdx.x] += red[threadIdx.x + s];
        __syncthreads();
    }
    float f = 1.0f / (fmaxf(sqrtf(red[0]), EPSN) * 32.0f);
    for (int c = threadIdx.x; c < cols; c += 256) wn[(size_t)r * cols + c] = f2bf(row[c] * f);
}

// C[M][N] = A[M][K] @ B[N][K]^T, A/B bf16, C fp32. m97 structure:
// 128x128 tile, BK=32, 4 waves, each wave 64x64 = 4x4 MFMA tiles, global_load_lds w=16.
__global__ __launch_bounds__(256) void gemm_mfma(const short* __restrict__ A,
                                                 const short* __restrict__ B,
                                                 float* __restrict__ C,
                                                 int M, int N, int K,
                                                 const float* __restrict__ resid) {
    __shared__ __align__(16) short As[128 * 32];   // [row][k], unpadded (global_load_lds order)
    __shared__ __align__(16) short Bs[128 * 32];
    const int tid = threadIdx.x;
    const int wv = tid >> 6, lane = tid & 63;
    const int l16 = lane & 15, quad = lane >> 4;
    const int wr = wv >> 1, wc = wv & 1;
    const int bm0 = blockIdx.y * 128, bn0 = blockIdx.x * 128;
    const int grow = lane >> 2;           // row within 16-row chunk
    const int gk = (lane & 3) * 8;        // k-element offset (8 shorts = 16 B)

    floatx4 acc[4][4];
    #pragma unroll
    for (int i = 0; i < 4; i++)
        #pragma unroll
        for (int j = 0; j < 4; j++) acc[i][j] = (floatx4){0.f, 0.f, 0.f, 0.f};

    for (int kk = 0; kk < K; kk += 32) {
        __syncthreads();
        #pragma unroll
        for (int j = 0; j < 2; j++) {
            const int rA = bm0 + wv * 32 + j * 16 + grow;
            const int rB = bn0 + wv * 32 + j * 16 + grow;
            async16(&As[(wv * 32 + j * 16) * 32], A + (size_t)rA * K + kk + gk);
            async16(&Bs[(wv * 32 + j * 16) * 32], B + (size_t)rB * K + kk + gk);
        }
        asm volatile("s_waitcnt vmcnt(0)" ::: "memory");
        __syncthreads();
        short8 aA[4], bB[4];
        #pragma unroll
        for (int i = 0; i < 4; i++)
            aA[i] = *(const short8*)&As[(wr * 64 + i * 16 + l16) * 32 + quad * 8];
        #pragma unroll
        for (int j = 0; j < 4; j++)
            bB[j] = *(const short8*)&Bs[(wc * 64 + j * 16 + l16) * 32 + quad * 8];
        #pragma unroll
        for (int i = 0; i < 4; i++)
            #pragma unroll
            for (int j = 0; j < 4; j++)
                acc[i][j] = __builtin_amdgcn_mfma_f32_16x16x32_bf16(aA[i], bB[j], acc[i][j], 0, 0, 0);
    }
    #pragma unroll
    for (int i = 0; i < 4; i++)
        #pragma unroll
        for (int j = 0; j < 4; j++)
            #pragma unroll
            for (int r = 0; r < 4; r++) {
                const int row = bm0 + wr * 64 + i * 16 + quad * 4 + r;
                const int col = bn0 + wc * 64 + j * 16 + l16;
                const size_t idx = (size_t)row * N + col;
                float v = acc[i][j][r];
                if (resid) v = (v * 0.7f + resid[idx] * 0.3f) * 1.3130643285972254f;
                C[idx] = v;
            }
}

// Flash attention with bf16 MFMA; writes bf16 output for the out-projection.
__global__ __launch_bounds__(256) void attn_mfma(const float* __restrict__ qkv,
                                                 const float* __restrict__ memkv,
                                                 short* __restrict__ out) {
    const int n = 2048;
    const int bh = blockIdx.x;
    const int bb = bh >> 4, h = bh & 15;
    const int q0 = blockIdx.y * 64;
    const int tid = threadIdx.x;
    const int wave = tid >> 6;
    const int lane = tid & 63;
    const int l16 = lane & 15;
    const int quad = lane >> 4;

    __shared__ __align__(16) short Qs[64 * LDH];
    __shared__ __align__(16) short Ks[64 * LDH];
    __shared__ __align__(16) short Vt[64 * LDH];
    __shared__ __align__(16) short Ps[4][16 * LDH];

    {
        const int r = tid >> 2, part = tid & 3;
        const float* src = qkv + ((size_t)(bb * n + q0 + r)) * 3072 + h * 64 + part * 16;
        float v[16]; float ss = 0.f;
        #pragma unroll
        for (int i = 0; i < 16; i += 4) {
            float4 f = *(const float4*)(src + i);
            v[i] = f.x; v[i+1] = f.y; v[i+2] = f.z; v[i+3] = f.w;
            ss += f.x*f.x + f.y*f.y + f.z*f.z + f.w*f.w;
        }
        ss += __shfl_xor(ss, 1); ss += __shfl_xor(ss, 2);
        const float fn = 1.0f / fmaxf(sqrtf(ss), EPSN);
        #pragma unroll
        for (int i = 0; i < 16; i++) Qs[r * LDH + part * 16 + i] = f2bf(v[i] * fn);
    }
    __syncthreads();

    short8 aQ0, aQ1;
    {
        const short* p = &Qs[(wave * 16 + l16) * LDH + quad * 8];
        aQ0 = *(const short8*)p;
        aQ1 = *(const short8*)(p + 32);
    }

    floatx4 O[4];
    #pragma unroll
    for (int t = 0; t < 4; t++) O[t] = (floatx4){0.f, 0.f, 0.f, 0.f};
    float mrow[4], lrow[4];
    #pragma unroll
    for (int i = 0; i < 4; i++) { mrow[i] = -1e30f; lrow[i] = 0.f; }

    for (int tile = 0; tile < 33; tile++) {
        __syncthreads();
        {
            const int r = tid >> 2, part = tid & 3;
            float vk[16], vv[16]; float ssk = 0.f, ssv = 0.f;
            if (tile == 0) {
                if (r < 4) {
                    const float* pk = memkv + (size_t)(h * 4 + r) * 64 + part * 16;
                    const float* pv = memkv + (size_t)((16 + h) * 4 + r) * 64 + part * 16;
                    #pragma unroll
                    for (int i = 0; i < 16; i += 4) {
                        float4 a = *(const float4*)(pk + i);
                        float4 b = *(const float4*)(pv + i);
                        vk[i]=a.x; vk[i+1]=a.y; vk[i+2]=a.z; vk[i+3]=a.w;
                        vv[i]=b.x; vv[i+1]=b.y; vv[i+2]=b.z; vv[i+3]=b.w;
                        ssk += a.x*a.x + a.y*a.y + a.z*a.z + a.w*a.w;
                        ssv += b.x*b.x + b.y*b.y + b.z*b.z + b.w*b.w;
                    }
                } else {
                    #pragma unroll
                    for (int i = 0; i < 16; i++) { vk[i] = 0.f; vv[i] = 0.f; }
                }
            } else {
                const size_t base = ((size_t)(bb * n + (tile - 1) * 64 + r)) * 3072 + h * 64 + part * 16;
                #pragma unroll
                for (int i = 0; i < 16; i += 4) {
                    float4 a = *(const float4*)(qkv + base + 1024 + i);
                    float4 b = *(const float4*)(qkv + base + 2048 + i);
                    vk[i]=a.x; vk[i+1]=a.y; vk[i+2]=a.z; vk[i+3]=a.w;
                    vv[i]=b.x; vv[i+1]=b.y; vv[i+2]=b.z; vv[i+3]=b.w;
                    ssk += a.x*a.x + a.y*a.y + a.z*a.z + a.w*a.w;
                    ssv += b.x*b.x + b.y*b.y + b.z*b.z + b.w*b.w;
                }
            }
            ssk += __shfl_xor(ssk, 1); ssk += __shfl_xor(ssk, 2);
            ssv += __shfl_xor(ssv, 1); ssv += __shfl_xor(ssv, 2);
            const float fk = 8.0f / fmaxf(sqrtf(ssk), EPSN);
            const float fv = 8.0f / fmaxf(sqrtf(ssv), EPSN);
            #pragma unroll
            for (int i = 0; i < 16; i++) {
                Ks[r * LDH + part * 16 + i] = f2bf(vk[i] * fk);
                Vt[(part * 16 + i) * LDH + r] = f2bf(vv[i] * fv);
            }
        }
        __syncthreads();

        floatx4 S[4];
        #pragma unroll
        for (int t = 0; t < 4; t++) {
            const short* pb = &Ks[(t * 16 + l16) * LDH + quad * 8];
            short8 b0 = *(const short8*)pb;
            short8 b1 = *(const short8*)(pb + 32);
            floatx4 s = (floatx4){0.f, 0.f, 0.f, 0.f};
            s = __builtin_amdgcn_mfma_f32_16x16x32_bf16(aQ0, b0, s, 0, 0, 0);
            s = __builtin_amdgcn_mfma_f32_16x16x32_bf16(aQ1, b1, s, 0, 0, 0);
            S[t] = s;
        }
        if (tile == 0) {
            #pragma unroll
            for (int t = 0; t < 4; t++)
                if (t * 16 + l16 >= 4) { S[t][0] = S[t][1] = S[t][2] = S[t][3] = -1e30f; }
        }
        float alpha[4];
        #pragma unroll
        for (int i = 0; i < 4; i++) {
            float m = fmaxf(fmaxf(S[0][i], S[1][i]), fmaxf(S[2][i], S[3][i]));
            m = fmaxf(m, __shfl_xor(m, 1));
            m = fmaxf(m, __shfl_xor(m, 2));
            m = fmaxf(m, __shfl_xor(m, 4));
            m = fmaxf(m, __shfl_xor(m, 8));
            const float mnew = fmaxf(mrow[i], m);
            alpha[i] = __expf(mrow[i] - mnew);
            mrow[i] = mnew;
        }
        #pragma unroll
        for (int t = 0; t < 4; t++) {
            #pragma unroll
            for (int i = 0; i < 4; i++) S[t][i] = __expf(S[t][i] - mrow[i]);
        }
        #pragma unroll
        for (int i = 0; i < 4; i++) {
            float s = S[0][i] + S[1][i] + S[2][i] + S[3][i];
            s += __shfl_xor(s, 1); s += __shfl_xor(s, 2);
            s += __shfl_xor(s, 4); s += __shfl_xor(s, 8);
            lrow[i] = lrow[i] * alpha[i] + s;
        }
        short* pp = Ps[wave];
        #pragma unroll
        for (int t = 0; t < 4; t++) {
            #pragma unroll
            for (int i = 0; i < 4; i++) {
                O[t][i] *= alpha[i];
                pp[(quad * 4 + i) * LDH + t * 16 + l16] = f2bf(S[t][i]);
            }
        }
        short8 aP0, aP1;
        {
            const short* pa = &pp[l16 * LDH + quad * 8];
            aP0 = *(const short8*)pa;
            aP1 = *(const short8*)(pa + 32);
        }
        #pragma unroll
        for (int t = 0; t < 4; t++) {
            const short* pv2 = &Vt[(t * 16 + l16) * LDH + quad * 8];
            short8 b0 = *(const short8*)pv2;
            short8 b1 = *(const short8*)(pv2 + 32);
            O[t] = __builtin_amdgcn_mfma_f32_16x16x32_bf16(aP0, b0, O[t], 0, 0, 0);
            O[t] = __builtin_amdgcn_mfma_f32_16x16x32_bf16(aP1, b1, O[t], 0, 0, 0);
        }
    }

    #pragma unroll
    for (int i = 0; i < 4; i++) {
        const float inv = 1.0f / lrow[i];
        const int qrow = q0 + wave * 16 + quad * 4 + i;
        const size_t base = ((size_t)(bb * n + qrow)) * 1024 + h * 64 + l16;
        #pragma unroll
        for (int t = 0; t < 4; t++) out[base + t * 16] = f2bf(O[t][i] * inv);
    }
}

extern "C" void kernel_launch(void* const* d_in, const int* in_sizes, int n_in,
                              void* d_out, int out_size, void* d_ws, size_t ws_size,
                              hipStream_t stream) {
    const float* x      = (const float*)d_in[0];   // [2,2048,1024]
    const float* w_qkv  = (const float*)d_in[1];   // [3072,1024]
    const float* w_out  = (const float*)d_in[2];   // [1024,1024]
    const float* mem_kv = (const float*)d_in[3];   // [2,16,4,64]
    float* out = (float*)d_out;                    // [2,2048,1024]

    char* ws = (char*)d_ws;
    short* wnqkv_b = (short*)(ws);                         // 3072*1024*2 = 6 MB
    short* wnout_b = (short*)(ws + (6u << 20));            // 2 MB
    short* xb      = (short*)(ws + (8u << 20));            // 8 MB
    float* qkv     = (float*)(ws + (16u << 20));           // 48 MB
    short* attnb   = (short*)(ws + (64u << 20));           // 8 MB  (total 72 MB)

    cast_bf16<<<4096, 256, 0, stream>>>(x, xb);
    norm_rows<<<3072, 256, 0, stream>>>(w_qkv, wnqkv_b, 1024);
    norm_rows<<<1024, 256, 0, stream>>>(w_out, wnout_b, 1024);

    // qkv = xb @ wnqkv^T : M=4096, N=3072, K=1024
    gemm_mfma<<<dim3(3072 / 128, 4096 / 128), 256, 0, stream>>>(
        xb, wnqkv_b, qkv, 4096, 3072, 1024, nullptr);

    attn_mfma<<<dim3(32, 32), 256, 0, stream>>>(qkv, mem_kv, attnb);

    // out = attnb @ wnout^T + residual : M=4096, N=1024, K=1024
    gemm_mfma<<<dim3(1024 / 128, 4096 / 128), 256, 0, stream>>>(
        attnb, wnout_b, out, 4096, 1024, 1024, x);
}

// Round 4
// 310.334 us; speedup vs baseline: 12.4036x; 1.2062x over previous
//
#include <hip/hip_runtime.h>
#include <hip/hip_bf16.h>
#include <math.h>

// MP Attention: b=2, n=2048, dim=1024, h=16, d=64.
//  0. cast_bf16:  xb = bf16(x)
//  1. norm_rows:  wn = bf16( w / (max(||row||,eps) * 32) )
//  2. gemm_mfma:  qkv[4096][3072] (fp32) = xb @ wn_qkv^T      (bf16 MFMA, m97 structure)
//  3. prep_qkv:   pixel-norm + bf16 relayout: Qb[bh][n][64], Kb[bh][2112][64]
//                 (mem_kv rows 0..3, keys 4..2051, zeros 2052..2111), Vt[bh][64][2112]
//  4. attn_mfma:  flash attention, bf16 MFMA, staging = pure bf16 copies; writes bf16
//  5. gemm_mfma:  out = attn_b @ wn_out^T + fused MP residual (fp32 out)

#define EPSN 1e-4f
#define LDH 72
#define NKEY 2112   // 4 memkv + 2048 + 60 zero-pad (33 tiles of 64)

typedef __attribute__((ext_vector_type(8))) short short8;
typedef __attribute__((ext_vector_type(4))) short short4v;
typedef __attribute__((ext_vector_type(4))) float floatx4;

typedef __attribute__((address_space(1))) const void g_void;
typedef __attribute__((address_space(3))) void lds_void;

__device__ __forceinline__ void async16(void* lds, const void* g) {
    __builtin_amdgcn_global_load_lds((g_void*)g, (lds_void*)lds, 16, 0, 0);
}

__device__ __forceinline__ short f2bf(float f) {
    union { float f; unsigned u; } c{f};
    unsigned r = (c.u + 0x7FFF + ((c.u >> 16) & 1)) >> 16;
    return (short)r;
}

__global__ __launch_bounds__(256) void cast_bf16(const float* __restrict__ in,
                                                 short* __restrict__ out) {
    int i = (blockIdx.x * 256 + threadIdx.x) * 4;
    float4 v = *(const float4*)(in + i);
    short4v s = {f2bf(v.x), f2bf(v.y), f2bf(v.z), f2bf(v.w)};
    *(short4v*)(out + i) = s;
}

__global__ __launch_bounds__(256) void norm_rows(const float* __restrict__ w,
                                                 short* __restrict__ wn, int cols) {
    __shared__ float red[256];
    int r = blockIdx.x;
    const float* row = w + (size_t)r * cols;
    float ss = 0.0f;
    for (int c = threadIdx.x; c < cols; c += 256) { float v = row[c]; ss += v * v; }
    red[threadIdx.x] = ss;
    __syncthreads();
    for (int s = 128; s > 0; s >>= 1) {
        if (threadIdx.x < s) red[threadIdx.x] += red[threadIdx.x + s];
        __syncthreads();
    }
    float f = 1.0f / (fmaxf(sqrtf(red[0]), EPSN) * 32.0f);
    for (int c = threadIdx.x; c < cols; c += 256) wn[(size_t)r * cols + c] = f2bf(row[c] * f);
}

// C[M][N] = A[M][K] @ B[N][K]^T, A/B bf16, C fp32 (m97 structure).
__global__ __launch_bounds__(256) void gemm_mfma(const short* __restrict__ A,
                                                 const short* __restrict__ B,
                                                 float* __restrict__ C,
                                                 int M, int N, int K,
                                                 const float* __restrict__ resid) {
    __shared__ __align__(16) short As[128 * 32];
    __shared__ __align__(16) short Bs[128 * 32];
    const int tid = threadIdx.x;
    const int wv = tid >> 6, lane = tid & 63;
    const int l16 = lane & 15, quad = lane >> 4;
    const int wr = wv >> 1, wc = wv & 1;
    const int bm0 = blockIdx.y * 128, bn0 = blockIdx.x * 128;
    const int grow = lane >> 2;
    const int gk = (lane & 3) * 8;

    floatx4 acc[4][4];
    #pragma unroll
    for (int i = 0; i < 4; i++)
        #pragma unroll
        for (int j = 0; j < 4; j++) acc[i][j] = (floatx4){0.f, 0.f, 0.f, 0.f};

    for (int kk = 0; kk < K; kk += 32) {
        __syncthreads();
        #pragma unroll
        for (int j = 0; j < 2; j++) {
            const int rA = bm0 + wv * 32 + j * 16 + grow;
            const int rB = bn0 + wv * 32 + j * 16 + grow;
            async16(&As[(wv * 32 + j * 16) * 32], A + (size_t)rA * K + kk + gk);
            async16(&Bs[(wv * 32 + j * 16) * 32], B + (size_t)rB * K + kk + gk);
        }
        asm volatile("s_waitcnt vmcnt(0)" ::: "memory");
        __syncthreads();
        short8 aA[4], bB[4];
        #pragma unroll
        for (int i = 0; i < 4; i++)
            aA[i] = *(const short8*)&As[(wr * 64 + i * 16 + l16) * 32 + quad * 8];
        #pragma unroll
        for (int j = 0; j < 4; j++)
            bB[j] = *(const short8*)&Bs[(wc * 64 + j * 16 + l16) * 32 + quad * 8];
        #pragma unroll
        for (int i = 0; i < 4; i++)
            #pragma unroll
            for (int j = 0; j < 4; j++)
                acc[i][j] = __builtin_amdgcn_mfma_f32_16x16x32_bf16(aA[i], bB[j], acc[i][j], 0, 0, 0);
    }
    #pragma unroll
    for (int i = 0; i < 4; i++)
        #pragma unroll
        for (int j = 0; j < 4; j++)
            #pragma unroll
            for (int r = 0; r < 4; r++) {
                const int row = bm0 + wr * 64 + i * 16 + quad * 4 + r;
                const int col = bn0 + wc * 64 + j * 16 + l16;
                const size_t idx = (size_t)row * N + col;
                float v = acc[i][j][r];
                if (resid) v = (v * 0.7f + resid[idx] * 0.3f) * 1.3130643285972254f;
                C[idx] = v;
            }
}

// One-shot pixel-norm + bf16 relayout of q,k,v (+ mem_kv + zero pad).
__global__ __launch_bounds__(256) void prep_qkv(const float* __restrict__ qkv,
                                                const float* __restrict__ memkv,
                                                short* __restrict__ Qb,
                                                short* __restrict__ Kb,
                                                short* __restrict__ Vt) {
    __shared__ short Ls[64 * LDH];
    const int bh = blockIdx.x, bb = bh >> 4, h = bh & 15;
    const int tile = blockIdx.y;     // 0..31 tokens; 32 = memkv + pad
    const int tid = threadIdx.x;
    const int r = tid >> 2, part = tid & 3;

    if (tile < 32) {
        const int tok = tile * 64 + r;
        const float* base = qkv + ((size_t)(bb * 2048 + tok)) * 3072 + h * 64 + part * 16;
        float q[16], k[16], v[16];
        float ssq = 0.f, ssk = 0.f, ssv = 0.f;
        #pragma unroll
        for (int i = 0; i < 16; i += 4) {
            float4 a = *(const float4*)(base + i);
            float4 b = *(const float4*)(base + 1024 + i);
            float4 c = *(const float4*)(base + 2048 + i);
            q[i]=a.x; q[i+1]=a.y; q[i+2]=a.z; q[i+3]=a.w;
            k[i]=b.x; k[i+1]=b.y; k[i+2]=b.z; k[i+3]=b.w;
            v[i]=c.x; v[i+1]=c.y; v[i+2]=c.z; v[i+3]=c.w;
            ssq += a.x*a.x + a.y*a.y + a.z*a.z + a.w*a.w;
            ssk += b.x*b.x + b.y*b.y + b.z*b.z + b.w*b.w;
            ssv += c.x*c.x + c.y*c.y + c.z*c.z + c.w*c.w;
        }
        ssq += __shfl_xor(ssq, 1); ssq += __shfl_xor(ssq, 2);
        ssk += __shfl_xor(ssk, 1); ssk += __shfl_xor(ssk, 2);
        ssv += __shfl_xor(ssv, 1); ssv += __shfl_xor(ssv, 2);
        const float fq = 1.0f / fmaxf(sqrtf(ssq), EPSN);
        const float fk = 8.0f / fmaxf(sqrtf(ssk), EPSN);
        const float fv = 8.0f / fmaxf(sqrtf(ssv), EPSN);
        short8 oq, ok;
        #pragma unroll
        for (int i = 0; i < 8; i++) { oq[i] = f2bf(q[i] * fq); ok[i] = f2bf(k[i] * fk); }
        short8 oq1, ok1;
        #pragma unroll
        for (int i = 0; i < 8; i++) { oq1[i] = f2bf(q[8+i] * fq); ok1[i] = f2bf(k[8+i] * fk); }
        short* qd = Qb + ((size_t)bh * 2048 + tok) * 64 + part * 16;
        *(short8*)qd = oq; *(short8*)(qd + 8) = oq1;
        short* kd = Kb + ((size_t)bh * NKEY + 4 + tok) * 64 + part * 16;
        *(short8*)kd = ok; *(short8*)(kd + 8) = ok1;
        // V: transpose through LDS
        #pragma unroll
        for (int i = 0; i < 16; i++) Ls[r * LDH + part * 16 + i] = f2bf(v[i] * fv);
        __syncthreads();
        // thread (d=r, keys part*16..part*16+15) gathers a transposed run
        short4v o[4];
        #pragma unroll
        for (int j = 0; j < 16; j++) o[j >> 2][j & 3] = Ls[(part * 16 + j) * LDH + r];
        short* vd = Vt + ((size_t)bh * 64 + r) * NKEY + 4 + tile * 64 + part * 16;
        #pragma unroll
        for (int j = 0; j < 4; j++) *(short4v*)(vd + j * 4) = o[j];
    } else {
        if (r < 4) {   // threads 0..15: mem_kv rows
            const float* pk = memkv + (size_t)(h * 4 + r) * 64 + part * 16;
            const float* pv = memkv + (size_t)((16 + h) * 4 + r) * 64 + part * 16;
            float k[16], v[16]; float ssk = 0.f, ssv = 0.f;
            #pragma unroll
            for (int i = 0; i < 16; i += 4) {
                float4 a = *(const float4*)(pk + i);
                float4 b = *(const float4*)(pv + i);
                k[i]=a.x; k[i+1]=a.y; k[i+2]=a.z; k[i+3]=a.w;
                v[i]=b.x; v[i+1]=b.y; v[i+2]=b.z; v[i+3]=b.w;
                ssk += a.x*a.x + a.y*a.y + a.z*a.z + a.w*a.w;
                ssv += b.x*b.x + b.y*b.y + b.z*b.z + b.w*b.w;
            }
            ssk += __shfl_xor(ssk, 1); ssk += __shfl_xor(ssk, 2);
            ssv += __shfl_xor(ssv, 1); ssv += __shfl_xor(ssv, 2);
            const float fk = 8.0f / fmaxf(sqrtf(ssk), EPSN);
            const float fv = 8.0f / fmaxf(sqrtf(ssv), EPSN);
            short* kd = Kb + ((size_t)bh * NKEY + r) * 64 + part * 16;
            #pragma unroll
            for (int i = 0; i < 16; i++) kd[i] = f2bf(k[i] * fk);
            #pragma unroll
            for (int i = 0; i < 16; i++)
                Vt[((size_t)bh * 64 + part * 16 + i) * NKEY + r] = f2bf(v[i] * fv);
        }
        // zero pad: Kb rows 2052..2111 (3840 shorts)
        for (int p = tid; p < 480; p += 256)
            *(short8*)(Kb + ((size_t)bh * NKEY + 2052) * 64 + p * 8) = (short8){0,0,0,0,0,0,0,0};
        // zero pad: Vt cols 2052..2111 for all 64 d-rows (64*60 shorts, 4-aligned)
        for (int p = tid; p < 960; p += 256) {
            int row = p / 15, c = p % 15;
            *(short4v*)(Vt + ((size_t)bh * 64 + row) * NKEY + 2052 + c * 4) = (short4v){0,0,0,0};
        }
    }
}

// Flash attention; all inputs pre-normalized bf16. Writes bf16.
__global__ __launch_bounds__(256) void attn_mfma(const short* __restrict__ Qb,
                                                 const short* __restrict__ Kb,
                                                 const short* __restrict__ Vt,
                                                 short* __restrict__ out) {
    const int bh = blockIdx.x;
    const int q0 = blockIdx.y * 64;
    const int tid = threadIdx.x;
    const int wave = tid >> 6;
    const int lane = tid & 63;
    const int l16 = lane & 15;
    const int quad = lane >> 4;

    __shared__ __align__(16) short Ks[64 * LDH];
    __shared__ __align__(16) short Vs[64 * LDH];
    __shared__ __align__(16) short Ps[4][16 * LDH];

    // Q A-fragments straight from global (rows wave*16 + l16)
    const short* qp = Qb + ((size_t)bh * 2048 + q0 + wave * 16 + l16) * 64 + quad * 8;
    short8 aQ0 = *(const short8*)qp;
    short8 aQ1 = *(const short8*)(qp + 32);

    floatx4 O[4];
    #pragma unroll
    for (int t = 0; t < 4; t++) O[t] = (floatx4){0.f, 0.f, 0.f, 0.f};
    float mrow[4], lrow[4];
    #pragma unroll
    for (int i = 0; i < 4; i++) { mrow[i] = -1e30f; lrow[i] = 0.f; }

    const int srow = tid >> 3, sch = tid & 7;   // staging: 8 threads/row
    for (int tile = 0; tile < 33; tile++) {
        __syncthreads();
        #pragma unroll
        for (int rnd = 0; rnd < 2; rnd++) {
            const int row = rnd * 32 + srow;
            short8 kv = *(const short8*)(Kb + ((size_t)bh * NKEY + tile * 64 + row) * 64 + sch * 8);
            *(short8*)&Ks[row * LDH + sch * 8] = kv;
            short8 vv = *(const short8*)(Vt + ((size_t)bh * 64 + row) * NKEY + tile * 64 + sch * 8);
            *(short8*)&Vs[row * LDH + sch * 8] = vv;
        }
        __syncthreads();

        floatx4 S[4];
        #pragma unroll
        for (int t = 0; t < 4; t++) {
            const short* pb = &Ks[(t * 16 + l16) * LDH + quad * 8];
            short8 b0 = *(const short8*)pb;
            short8 b1 = *(const short8*)(pb + 32);
            floatx4 s = (floatx4){0.f, 0.f, 0.f, 0.f};
            s = __builtin_amdgcn_mfma_f32_16x16x32_bf16(aQ0, b0, s, 0, 0, 0);
            s = __builtin_amdgcn_mfma_f32_16x16x32_bf16(aQ1, b1, s, 0, 0, 0);
            S[t] = s;
        }
        if (tile == 32) {   // keys 2052..2111 are padding
            #pragma unroll
            for (int t = 0; t < 4; t++)
                if (t * 16 + l16 >= 4) { S[t][0] = S[t][1] = S[t][2] = S[t][3] = -1e30f; }
        }
        float alpha[4];
        #pragma unroll
        for (int i = 0; i < 4; i++) {
            float m = fmaxf(fmaxf(S[0][i], S[1][i]), fmaxf(S[2][i], S[3][i]));
            m = fmaxf(m, __shfl_xor(m, 1));
            m = fmaxf(m, __shfl_xor(m, 2));
            m = fmaxf(m, __shfl_xor(m, 4));
            m = fmaxf(m, __shfl_xor(m, 8));
            const float mnew = fmaxf(mrow[i], m);
            alpha[i] = __expf(mrow[i] - mnew);
            mrow[i] = mnew;
        }
        #pragma unroll
        for (int t = 0; t < 4; t++) {
            #pragma unroll
            for (int i = 0; i < 4; i++) S[t][i] = __expf(S[t][i] - mrow[i]);
        }
        #pragma unroll
        for (int i = 0; i < 4; i++) {
            float s = S[0][i] + S[1][i] + S[2][i] + S[3][i];
            s += __shfl_xor(s, 1); s += __shfl_xor(s, 2);
            s += __shfl_xor(s, 4); s += __shfl_xor(s, 8);
            lrow[i] = lrow[i] * alpha[i] + s;
        }
        short* pp = Ps[wave];
        #pragma unroll
        for (int t = 0; t < 4; t++) {
            #pragma unroll
            for (int i = 0; i < 4; i++) {
                O[t][i] *= alpha[i];
                pp[(quad * 4 + i) * LDH + t * 16 + l16] = f2bf(S[t][i]);
            }
        }
        short8 aP0, aP1;
        {
            const short* pa = &pp[l16 * LDH + quad * 8];
            aP0 = *(const short8*)pa;
            aP1 = *(const short8*)(pa + 32);
        }
        #pragma unroll
        for (int t = 0; t < 4; t++) {
            const short* pv2 = &Vs[(t * 16 + l16) * LDH + quad * 8];
            short8 b0 = *(const short8*)pv2;
            short8 b1 = *(const short8*)(pv2 + 32);
            O[t] = __builtin_amdgcn_mfma_f32_16x16x32_bf16(aP0, b0, O[t], 0, 0, 0);
            O[t] = __builtin_amdgcn_mfma_f32_16x16x32_bf16(aP1, b1, O[t], 0, 0, 0);
        }
    }

    const int bb = bh >> 4, h = bh & 15;
    #pragma unroll
    for (int i = 0; i < 4; i++) {
        const float inv = 1.0f / lrow[i];
        const int qrow = q0 + wave * 16 + quad * 4 + i;
        const size_t base = ((size_t)(bb * 2048 + qrow)) * 1024 + h * 64 + l16;
        #pragma unroll
        for (int t = 0; t < 4; t++) out[base + t * 16] = f2bf(O[t][i] * inv);
    }
}

extern "C" void kernel_launch(void* const* d_in, const int* in_sizes, int n_in,
                              void* d_out, int out_size, void* d_ws, size_t ws_size,
                              hipStream_t stream) {
    const float* x      = (const float*)d_in[0];   // [2,2048,1024]
    const float* w_qkv  = (const float*)d_in[1];   // [3072,1024]
    const float* w_out  = (const float*)d_in[2];   // [1024,1024]
    const float* mem_kv = (const float*)d_in[3];   // [2,16,4,64]
    float* out = (float*)d_out;                    // [2,2048,1024]

    char* ws = (char*)d_ws;
    short* wnqkv_b = (short*)(ws);                    // 6 MB
    short* wnout_b = (short*)(ws + (6u << 20));       // 2 MB
    short* xb      = (short*)(ws + (8u << 20));       // 8 MB
    float* qkv     = (float*)(ws + (16u << 20));      // 48 MB
    short* attnb   = (short*)(ws + (64u << 20));      // 8 MB
    short* Qb      = (short*)(ws + (72u << 20));      // 8 MB
    short* Kb      = (short*)(ws + (80u << 20));      // 8.25 MB
    short* Vt      = (short*)(ws + (89u << 20));      // 8.25 MB (total 98 MB)

    cast_bf16<<<4096, 256, 0, stream>>>(x, xb);
    norm_rows<<<3072, 256, 0, stream>>>(w_qkv, wnqkv_b, 1024);
    norm_rows<<<1024, 256, 0, stream>>>(w_out, wnout_b, 1024);

    // qkv = xb @ wnqkv^T : M=4096, N=3072, K=1024
    gemm_mfma<<<dim3(3072 / 128, 4096 / 128), 256, 0, stream>>>(
        xb, wnqkv_b, qkv, 4096, 3072, 1024, nullptr);

    prep_qkv<<<dim3(32, 33), 256, 0, stream>>>(qkv, mem_kv, Qb, Kb, Vt);

    attn_mfma<<<dim3(32, 32), 256, 0, stream>>>(Qb, Kb, Vt, attnb);

    // out = attnb @ wnout^T + residual : M=4096, N=1024, K=1024
    gemm_mfma<<<dim3(1024 / 128, 4096 / 128), 256, 0, stream>>>(
        attnb, wnout_b, out, 4096, 1024, 1024, x);
}

// Round 5
// 264.539 us; speedup vs baseline: 14.5508x; 1.1731x over previous
//
#include <hip/hip_runtime.h>
#include <hip/hip_bf16.h>
#include <math.h>

// MP Attention: b=2, n=2048, dim=1024, h=16, d=64.
//  0. cast_bf16:  xb = bf16(x)
//  1. norm_rows:  wn = bf16( w / (max(||row||,eps) * 32) )
//  2. gemm_mfma:  qkvb[4096][3072] (bf16) = xb @ wn_qkv^T
//  3. prep_qkv:   pixel-norm + relayout: Qb (x log2e), Kb (memkv rows 0..3, keys,
//                 zero pad to 2112), Vt transposed
//  4. attn_mfma:  flash attention, FIXED-SHIFT softmax (|S|<=8*log2e<12, so
//                 P=exp2(S-12), no running max / alpha / rescale; l deferred)
//  5. gemm_mfma:  out = attnb @ wn_out^T + fused MP residual (fp32 out)

#define EPSN 1e-4f
#define LDH 72
#define NKEY 2112
#define LOG2E 1.4426950408889634f

typedef __attribute__((ext_vector_type(8))) short short8;
typedef __attribute__((ext_vector_type(4))) short short4v;
typedef __attribute__((ext_vector_type(4))) float floatx4;

typedef __attribute__((address_space(1))) const void g_void;
typedef __attribute__((address_space(3))) void lds_void;

__device__ __forceinline__ void async16(void* lds, const void* g) {
    __builtin_amdgcn_global_load_lds((g_void*)g, (lds_void*)lds, 16, 0, 0);
}

__device__ __forceinline__ short f2bf(float f) {   // RNE
    union { float f; unsigned u; } c{f};
    unsigned r = (c.u + 0x7FFF + ((c.u >> 16) & 1)) >> 16;
    return (short)r;
}
__device__ __forceinline__ short f2bf_fast(float f) {  // round-half-up (P in [0,1])
    union { float f; unsigned u; } c{f};
    return (short)((c.u + 0x8000) >> 16);
}
__device__ __forceinline__ float bf2f(short s) {
    union { unsigned u; float f; } c;
    c.u = ((unsigned)(unsigned short)s) << 16;
    return c.f;
}

__global__ __launch_bounds__(256) void cast_bf16(const float* __restrict__ in,
                                                 short* __restrict__ out) {
    int i = (blockIdx.x * 256 + threadIdx.x) * 4;
    float4 v = *(const float4*)(in + i);
    short4v s = {f2bf(v.x), f2bf(v.y), f2bf(v.z), f2bf(v.w)};
    *(short4v*)(out + i) = s;
}

__global__ __launch_bounds__(256) void norm_rows(const float* __restrict__ w,
                                                 short* __restrict__ wn, int cols) {
    __shared__ float red[256];
    int r = blockIdx.x;
    const float* row = w + (size_t)r * cols;
    float ss = 0.0f;
    for (int c = threadIdx.x; c < cols; c += 256) { float v = row[c]; ss += v * v; }
    red[threadIdx.x] = ss;
    __syncthreads();
    for (int s = 128; s > 0; s >>= 1) {
        if (threadIdx.x < s) red[threadIdx.x] += red[threadIdx.x + s];
        __syncthreads();
    }
    float f = 1.0f / (fmaxf(sqrtf(red[0]), EPSN) * 32.0f);
    for (int c = threadIdx.x; c < cols; c += 256) wn[(size_t)r * cols + c] = f2bf(row[c] * f);
}

// C[M][N] = A[M][K] @ B[N][K]^T, A/B bf16. Writes bf16 (Cb) or fp32 (C, + residual).
__global__ __launch_bounds__(256) void gemm_mfma(const short* __restrict__ A,
                                                 const short* __restrict__ B,
                                                 float* __restrict__ C,
                                                 short* __restrict__ Cb,
                                                 int M, int N, int K,
                                                 const float* __restrict__ resid) {
    __shared__ __align__(16) short As[128 * 32];
    __shared__ __align__(16) short Bs[128 * 32];
    const int tid = threadIdx.x;
    const int wv = tid >> 6, lane = tid & 63;
    const int l16 = lane & 15, quad = lane >> 4;
    const int wr = wv >> 1, wc = wv & 1;
    const int bm0 = blockIdx.y * 128, bn0 = blockIdx.x * 128;
    const int grow = lane >> 2;
    const int gk = (lane & 3) * 8;

    floatx4 acc[4][4];
    #pragma unroll
    for (int i = 0; i < 4; i++)
        #pragma unroll
        for (int j = 0; j < 4; j++) acc[i][j] = (floatx4){0.f, 0.f, 0.f, 0.f};

    for (int kk = 0; kk < K; kk += 32) {
        __syncthreads();
        #pragma unroll
        for (int j = 0; j < 2; j++) {
            const int rA = bm0 + wv * 32 + j * 16 + grow;
            const int rB = bn0 + wv * 32 + j * 16 + grow;
            async16(&As[(wv * 32 + j * 16) * 32], A + (size_t)rA * K + kk + gk);
            async16(&Bs[(wv * 32 + j * 16) * 32], B + (size_t)rB * K + kk + gk);
        }
        asm volatile("s_waitcnt vmcnt(0)" ::: "memory");
        __syncthreads();
        short8 aA[4], bB[4];
        #pragma unroll
        for (int i = 0; i < 4; i++)
            aA[i] = *(const short8*)&As[(wr * 64 + i * 16 + l16) * 32 + quad * 8];
        #pragma unroll
        for (int j = 0; j < 4; j++)
            bB[j] = *(const short8*)&Bs[(wc * 64 + j * 16 + l16) * 32 + quad * 8];
        #pragma unroll
        for (int i = 0; i < 4; i++)
            #pragma unroll
            for (int j = 0; j < 4; j++)
                acc[i][j] = __builtin_amdgcn_mfma_f32_16x16x32_bf16(aA[i], bB[j], acc[i][j], 0, 0, 0);
    }
    #pragma unroll
    for (int i = 0; i < 4; i++)
        #pragma unroll
        for (int j = 0; j < 4; j++)
            #pragma unroll
            for (int r = 0; r < 4; r++) {
                const int row = bm0 + wr * 64 + i * 16 + quad * 4 + r;
                const int col = bn0 + wc * 64 + j * 16 + l16;
                const size_t idx = (size_t)row * N + col;
                float v = acc[i][j][r];
                if (resid) v = (v * 0.7f + resid[idx] * 0.3f) * 1.3130643285972254f;
                if (Cb) Cb[idx] = f2bf(v);
                else    C[idx]  = v;
            }
}

// One-shot pixel-norm + relayout from bf16 qkv.
// Qb scaled by log2e (exp2-domain scores); Kb rows: 0..3 memkv, 4..2051 keys, pad 0.
__global__ __launch_bounds__(256) void prep_qkv(const short* __restrict__ qkvb,
                                                const float* __restrict__ memkv,
                                                short* __restrict__ Qb,
                                                short* __restrict__ Kb,
                                                short* __restrict__ Vt) {
    __shared__ short Ls[64 * LDH];
    const int bh = blockIdx.x, bb = bh >> 4, h = bh & 15;
    const int tile = blockIdx.y;
    const int tid = threadIdx.x;
    const int r = tid >> 2, part = tid & 3;

    if (tile < 32) {
        const int tok = tile * 64 + r;
        const short* base = qkvb + ((size_t)(bb * 2048 + tok)) * 3072 + h * 64 + part * 16;
        float q[16], k[16], v[16];
        float ssq = 0.f, ssk = 0.f, ssv = 0.f;
        short8 a0 = *(const short8*)base,          a1 = *(const short8*)(base + 8);
        short8 b0 = *(const short8*)(base + 1024), b1 = *(const short8*)(base + 1032);
        short8 c0 = *(const short8*)(base + 2048), c1 = *(const short8*)(base + 2056);
        #pragma unroll
        for (int i = 0; i < 8; i++) {
            q[i] = bf2f(a0[i]); q[8+i] = bf2f(a1[i]);
            k[i] = bf2f(b0[i]); k[8+i] = bf2f(b1[i]);
            v[i] = bf2f(c0[i]); v[8+i] = bf2f(c1[i]);
        }
        #pragma unroll
        for (int i = 0; i < 16; i++) { ssq += q[i]*q[i]; ssk += k[i]*k[i]; ssv += v[i]*v[i]; }
        ssq += __shfl_xor(ssq, 1); ssq += __shfl_xor(ssq, 2);
        ssk += __shfl_xor(ssk, 1); ssk += __shfl_xor(ssk, 2);
        ssv += __shfl_xor(ssv, 1); ssv += __shfl_xor(ssv, 2);
        const float fq = LOG2E / fmaxf(sqrtf(ssq), EPSN);
        const float fk = 8.0f / fmaxf(sqrtf(ssk), EPSN);
        const float fv = 8.0f / fmaxf(sqrtf(ssv), EPSN);
        short8 oq, ok, oq1, ok1;
        #pragma unroll
        for (int i = 0; i < 8; i++) { oq[i] = f2bf(q[i] * fq); ok[i] = f2bf(k[i] * fk); }
        #pragma unroll
        for (int i = 0; i < 8; i++) { oq1[i] = f2bf(q[8+i] * fq); ok1[i] = f2bf(k[8+i] * fk); }
        short* qd = Qb + ((size_t)bh * 2048 + tok) * 64 + part * 16;
        *(short8*)qd = oq; *(short8*)(qd + 8) = oq1;
        short* kd = Kb + ((size_t)bh * NKEY + 4 + tok) * 64 + part * 16;
        *(short8*)kd = ok; *(short8*)(kd + 8) = ok1;
        #pragma unroll
        for (int i = 0; i < 16; i++) Ls[r * LDH + part * 16 + i] = f2bf(v[i] * fv);
        __syncthreads();
        short4v o[4];
        #pragma unroll
        for (int j = 0; j < 16; j++) o[j >> 2][j & 3] = Ls[(part * 16 + j) * LDH + r];
        short* vd = Vt + ((size_t)bh * 64 + r) * NKEY + 4 + tile * 64 + part * 16;
        #pragma unroll
        for (int j = 0; j < 4; j++) *(short4v*)(vd + j * 4) = o[j];
    } else {
        if (r < 4) {
            const float* pk = memkv + (size_t)(h * 4 + r) * 64 + part * 16;
            const float* pv = memkv + (size_t)((16 + h) * 4 + r) * 64 + part * 16;
            float k[16], v[16]; float ssk = 0.f, ssv = 0.f;
            #pragma unroll
            for (int i = 0; i < 16; i += 4) {
                float4 a = *(const float4*)(pk + i);
                float4 b = *(const float4*)(pv + i);
                k[i]=a.x; k[i+1]=a.y; k[i+2]=a.z; k[i+3]=a.w;
                v[i]=b.x; v[i+1]=b.y; v[i+2]=b.z; v[i+3]=b.w;
                ssk += a.x*a.x + a.y*a.y + a.z*a.z + a.w*a.w;
                ssv += b.x*b.x + b.y*b.y + b.z*b.z + b.w*b.w;
            }
            ssk += __shfl_xor(ssk, 1); ssk += __shfl_xor(ssk, 2);
            ssv += __shfl_xor(ssv, 1); ssv += __shfl_xor(ssv, 2);
            const float fk = 8.0f / fmaxf(sqrtf(ssk), EPSN);
            const float fv = 8.0f / fmaxf(sqrtf(ssv), EPSN);
            short* kd = Kb + ((size_t)bh * NKEY + r) * 64 + part * 16;
            #pragma unroll
            for (int i = 0; i < 16; i++) kd[i] = f2bf(k[i] * fk);
            #pragma unroll
            for (int i = 0; i < 16; i++)
                Vt[((size_t)bh * 64 + part * 16 + i) * NKEY + r] = f2bf(v[i] * fv);
        }
        for (int p = tid; p < 480; p += 256)
            *(short8*)(Kb + ((size_t)bh * NKEY + 2052) * 64 + p * 8) = (short8){0,0,0,0,0,0,0,0};
        for (int p = tid; p < 960; p += 256) {
            int row = p / 15, c = p % 15;
            *(short4v*)(Vt + ((size_t)bh * 64 + row) * NKEY + 2052 + c * 4) = (short4v){0,0,0,0};
        }
    }
}

// Flash attention, fixed-shift softmax. Scores are exp2-domain (Q pre-scaled by
// log2e): |S| <= 8*log2e ~ 11.55 < 12, so P = exp2(S - 12) is safe. No running
// max, no rescale; l accumulated per-lane and reduced once at the end.
__global__ __launch_bounds__(256) void attn_mfma(const short* __restrict__ Qb,
                                                 const short* __restrict__ Kb,
                                                 const short* __restrict__ Vt,
                                                 short* __restrict__ out) {
    const int bh = blockIdx.x;
    const int q0 = blockIdx.y * 64;
    const int tid = threadIdx.x;
    const int wave = tid >> 6;
    const int lane = tid & 63;
    const int l16 = lane & 15;
    const int quad = lane >> 4;

    __shared__ __align__(16) short Ks[64 * LDH];
    __shared__ __align__(16) short Vs[64 * LDH];
    __shared__ __align__(16) short Ps[4][16 * LDH];

    const short* qp = Qb + ((size_t)bh * 2048 + q0 + wave * 16 + l16) * 64 + quad * 8;
    short8 aQ0 = *(const short8*)qp;
    short8 aQ1 = *(const short8*)(qp + 32);

    floatx4 O[4];
    #pragma unroll
    for (int t = 0; t < 4; t++) O[t] = (floatx4){0.f, 0.f, 0.f, 0.f};
    float lp[4] = {0.f, 0.f, 0.f, 0.f};   // per-lane partial denominators

    const int srow = tid >> 3, sch = tid & 7;
    for (int tile = 0; tile < 33; tile++) {
        __syncthreads();
        #pragma unroll
        for (int rnd = 0; rnd < 2; rnd++) {
            const int row = rnd * 32 + srow;
            short8 kv = *(const short8*)(Kb + ((size_t)bh * NKEY + tile * 64 + row) * 64 + sch * 8);
            *(short8*)&Ks[row * LDH + sch * 8] = kv;
            short8 vv = *(const short8*)(Vt + ((size_t)bh * 64 + row) * NKEY + tile * 64 + sch * 8);
            *(short8*)&Vs[row * LDH + sch * 8] = vv;
        }
        __syncthreads();

        floatx4 S[4];
        #pragma unroll
        for (int t = 0; t < 4; t++) {
            const short* pb = &Ks[(t * 16 + l16) * LDH + quad * 8];
            short8 b0 = *(const short8*)pb;
            short8 b1 = *(const short8*)(pb + 32);
            floatx4 s = (floatx4){-12.f, -12.f, -12.f, -12.f};  // baked-in shift
            s = __builtin_amdgcn_mfma_f32_16x16x32_bf16(aQ0, b0, s, 0, 0, 0);
            s = __builtin_amdgcn_mfma_f32_16x16x32_bf16(aQ1, b1, s, 0, 0, 0);
            S[t] = s;
        }
        if (tile == 32) {   // zero-padded keys 2052..2111 must get P=0
            #pragma unroll
            for (int t = 0; t < 4; t++)
                if (t * 16 + l16 >= 4) { S[t][0] = S[t][1] = S[t][2] = S[t][3] = -1e30f; }
        }
        short* pp = Ps[wave];
        #pragma unroll
        for (int t = 0; t < 4; t++) {
            #pragma unroll
            for (int i = 0; i < 4; i++) {
                float p = __builtin_amdgcn_exp2f(S[t][i]);
                lp[i] += p;
                pp[(quad * 4 + i) * LDH + t * 16 + l16] = f2bf_fast(p);
            }
        }
        short8 aP0, aP1;
        {
            const short* pa = &pp[l16 * LDH + quad * 8];
            aP0 = *(const short8*)pa;
            aP1 = *(const short8*)(pa + 32);
        }
        #pragma unroll
        for (int t = 0; t < 4; t++) {
            const short* pv2 = &Vs[(t * 16 + l16) * LDH + quad * 8];
            short8 b0 = *(const short8*)pv2;
            short8 b1 = *(const short8*)(pv2 + 32);
            O[t] = __builtin_amdgcn_mfma_f32_16x16x32_bf16(aP0, b0, O[t], 0, 0, 0);
            O[t] = __builtin_amdgcn_mfma_f32_16x16x32_bf16(aP1, b1, O[t], 0, 0, 0);
        }
    }

    const int bb = bh >> 4, h = bh & 15;
    #pragma unroll
    for (int i = 0; i < 4; i++) {
        float s = lp[i];
        s += __shfl_xor(s, 1); s += __shfl_xor(s, 2);
        s += __shfl_xor(s, 4); s += __shfl_xor(s, 8);
        const float inv = 1.0f / s;
        const int qrow = q0 + wave * 16 + quad * 4 + i;
        const size_t base = ((size_t)(bb * 2048 + qrow)) * 1024 + h * 64 + l16;
        #pragma unroll
        for (int t = 0; t < 4; t++) out[base + t * 16] = f2bf(O[t][i] * inv);
    }
}

extern "C" void kernel_launch(void* const* d_in, const int* in_sizes, int n_in,
                              void* d_out, int out_size, void* d_ws, size_t ws_size,
                              hipStream_t stream) {
    const float* x      = (const float*)d_in[0];
    const float* w_qkv  = (const float*)d_in[1];
    const float* w_out  = (const float*)d_in[2];
    const float* mem_kv = (const float*)d_in[3];
    float* out = (float*)d_out;

    char* ws = (char*)d_ws;
    short* wnqkv_b = (short*)(ws);                    // 6 MB
    short* wnout_b = (short*)(ws + (6u << 20));       // 2 MB
    short* xb      = (short*)(ws + (8u << 20));       // 8 MB
    short* qkvb    = (short*)(ws + (16u << 20));      // 24 MB (bf16)
    short* attnb   = (short*)(ws + (40u << 20));      // 8 MB
    short* Qb      = (short*)(ws + (48u << 20));      // 8 MB
    short* Kb      = (short*)(ws + (56u << 20));      // 8.25 MB
    short* Vt      = (short*)(ws + (65u << 20));      // 8.25 MB (total ~74 MB)

    cast_bf16<<<4096, 256, 0, stream>>>(x, xb);
    norm_rows<<<3072, 256, 0, stream>>>(w_qkv, wnqkv_b, 1024);
    norm_rows<<<1024, 256, 0, stream>>>(w_out, wnout_b, 1024);

    // qkvb = xb @ wnqkv^T : M=4096, N=3072, K=1024 (bf16 out)
    gemm_mfma<<<dim3(3072 / 128, 4096 / 128), 256, 0, stream>>>(
        xb, wnqkv_b, nullptr, qkvb, 4096, 3072, 1024, nullptr);

    prep_qkv<<<dim3(32, 33), 256, 0, stream>>>(qkvb, mem_kv, Qb, Kb, Vt);

    attn_mfma<<<dim3(32, 32), 256, 0, stream>>>(Qb, Kb, Vt, attnb);

    // out = attnb @ wnout^T + residual : M=4096, N=1024, K=1024 (fp32 out)
    gemm_mfma<<<dim3(1024 / 128, 4096 / 128), 256, 0, stream>>>(
        attnb, wnout_b, out, nullptr, 4096, 1024, 1024, x);
}

// Round 6
// 230.480 us; speedup vs baseline: 16.7009x; 1.1478x over previous
//
#include <hip/hip_runtime.h>
#include <hip/hip_bf16.h>
#include <math.h>

// MP Attention: b=2, n=2048, dim=1024, h=16, d=64.
//  0. cast_bf16:  xb = bf16(x)
//  1. norm_rows:  wn = bf16( w / (max(||row||,eps) * 32) )
//  2. gemm_mfma<128,128>: qkvb (bf16) = xb @ wn_qkv^T   -- dbuf-pipelined K-loop,
//       raw s_barrier + s_waitcnt vmcnt(N>0): prefetch stays in flight across barrier
//  3. prep_qkv:   pixel-norm + relayout (Qb x log2e, Kb with memkv+pad, Vt transposed)
//  4. attn_mfma:  512-thr blocks, 128 q-rows, fixed-shift exp2 softmax
//  5. gemm_mfma<64,64>: out = attnb @ wn_out^T + MP residual (1024 blocks for occupancy)

#define EPSN 1e-4f
#define LDH 72
#define NKEY 2112
#define LOG2E 1.4426950408889634f

typedef __attribute__((ext_vector_type(8))) short short8;
typedef __attribute__((ext_vector_type(4))) short short4v;
typedef __attribute__((ext_vector_type(4))) float floatx4;

typedef __attribute__((address_space(1))) const void g_void;
typedef __attribute__((address_space(3))) void lds_void;

__device__ __forceinline__ void async16(void* lds, const void* g) {
    __builtin_amdgcn_global_load_lds((g_void*)g, (lds_void*)lds, 16, 0, 0);
}

__device__ __forceinline__ short f2bf(float f) {   // RNE
    union { float f; unsigned u; } c{f};
    unsigned r = (c.u + 0x7FFF + ((c.u >> 16) & 1)) >> 16;
    return (short)r;
}
__device__ __forceinline__ short f2bf_fast(float f) {  // round-half-up (P in [0,1])
    union { float f; unsigned u; } c{f};
    return (short)((c.u + 0x8000) >> 16);
}
__device__ __forceinline__ float bf2f(short s) {
    union { unsigned u; float f; } c;
    c.u = ((unsigned)(unsigned short)s) << 16;
    return c.f;
}

__global__ __launch_bounds__(256) void cast_bf16(const float* __restrict__ in,
                                                 short* __restrict__ out) {
    int i = (blockIdx.x * 256 + threadIdx.x) * 4;
    float4 v = *(const float4*)(in + i);
    short4v s = {f2bf(v.x), f2bf(v.y), f2bf(v.z), f2bf(v.w)};
    *(short4v*)(out + i) = s;
}

__global__ __launch_bounds__(256) void norm_rows(const float* __restrict__ w,
                                                 short* __restrict__ wn, int cols) {
    __shared__ float red[256];
    int r = blockIdx.x;
    const float* row = w + (size_t)r * cols;
    float ss = 0.0f;
    for (int c = threadIdx.x; c < cols; c += 256) { float v = row[c]; ss += v * v; }
    red[threadIdx.x] = ss;
    __syncthreads();
    for (int s = 128; s > 0; s >>= 1) {
        if (threadIdx.x < s) red[threadIdx.x] += red[threadIdx.x + s];
        __syncthreads();
    }
    float f = 1.0f / (fmaxf(sqrtf(red[0]), EPSN) * 32.0f);
    for (int c = threadIdx.x; c < cols; c += 256) wn[(size_t)r * cols + c] = f2bf(row[c] * f);
}

// C[M][N] = A[M][K] @ B[N][K]^T, bf16 in, fp32 (C,+resid) or bf16 (Cb) out.
// Double-buffered pipelined K-loop: prefetch tile k+1 while computing tile k;
// raw s_barrier with vmcnt(inflight) so prefetch loads stay outstanding.
// 4 waves in 2x2; wave tile = MT/2 x NT/2.
template<int MT, int NT>
__global__ __launch_bounds__(256) void gemm_mfma(const short* __restrict__ A,
                                                 const short* __restrict__ B,
                                                 float* __restrict__ C,
                                                 short* __restrict__ Cb,
                                                 int M, int N, int K,
                                                 const float* __restrict__ resid) {
    constexpr int FI = MT / 32;          // frags per wave, M dir
    constexpr int FJ = NT / 32;
    constexpr int nA = MT / 64;          // async16 insts per wave for A tile
    constexpr int nB = NT / 64;
    __shared__ __align__(16) short As[2][MT * 32];
    __shared__ __align__(16) short Bs[2][NT * 32];
    const int tid = threadIdx.x;
    const int wv = tid >> 6, lane = tid & 63;
    const int l16 = lane & 15, quad = lane >> 4;
    const int wr = wv >> 1, wc = wv & 1;
    const int bm0 = blockIdx.y * MT, bn0 = blockIdx.x * NT;
    const int grow = lane >> 2;
    const int gk = (lane & 3) * 8;

    floatx4 acc[FI][FJ];
    #pragma unroll
    for (int i = 0; i < FI; i++)
        #pragma unroll
        for (int j = 0; j < FJ; j++) acc[i][j] = (floatx4){0.f, 0.f, 0.f, 0.f};

    const short* Abase = A + (size_t)(bm0 + wv * (MT / 4) + grow) * K + gk;
    const short* Bbase = B + (size_t)(bn0 + wv * (NT / 4) + grow) * K + gk;

    // preload tile 0 -> buf 0
    #pragma unroll
    for (int j = 0; j < nA; j++)
        async16(&As[0][(wv * (MT / 4) + j * 16) * 32], Abase + (size_t)(j * 16) * K);
    #pragma unroll
    for (int j = 0; j < nB; j++)
        async16(&Bs[0][(wv * (NT / 4) + j * 16) * 32], Bbase + (size_t)(j * 16) * K);

    const int NKI = K >> 5;
    for (int ki = 0; ki < NKI; ki++) {
        const int cur = ki & 1;
        if (ki + 1 < NKI) {
            const int nxt = cur ^ 1;
            const int off = (ki + 1) * 32;
            #pragma unroll
            for (int j = 0; j < nA; j++)
                async16(&As[nxt][(wv * (MT / 4) + j * 16) * 32], Abase + (size_t)(j * 16) * K + off);
            #pragma unroll
            for (int j = 0; j < nB; j++)
                async16(&Bs[nxt][(wv * (NT / 4) + j * 16) * 32], Bbase + (size_t)(j * 16) * K + off);
            if constexpr (nA + nB == 4)
                asm volatile("s_waitcnt vmcnt(4)" ::: "memory");
            else
                asm volatile("s_waitcnt vmcnt(2)" ::: "memory");
        } else {
            asm volatile("s_waitcnt vmcnt(0)" ::: "memory");
        }
        asm volatile("s_barrier" ::: "memory");   // tile ki resident in buf cur
        short8 aA[FI], bB[FJ];
        #pragma unroll
        for (int i = 0; i < FI; i++)
            aA[i] = *(const short8*)&As[cur][(wr * (MT / 2) + i * 16 + l16) * 32 + quad * 8];
        #pragma unroll
        for (int j = 0; j < FJ; j++)
            bB[j] = *(const short8*)&Bs[cur][(wc * (NT / 2) + j * 16 + l16) * 32 + quad * 8];
        #pragma unroll
        for (int i = 0; i < FI; i++)
            #pragma unroll
            for (int j = 0; j < FJ; j++)
                acc[i][j] = __builtin_amdgcn_mfma_f32_16x16x32_bf16(aA[i], bB[j], acc[i][j], 0, 0, 0);
        asm volatile("s_barrier" ::: "memory");   // buf cur free for tile ki+2's issue
    }
    #pragma unroll
    for (int i = 0; i < FI; i++)
        #pragma unroll
        for (int j = 0; j < FJ; j++)
            #pragma unroll
            for (int r = 0; r < 4; r++) {
                const int row = bm0 + wr * (MT / 2) + i * 16 + quad * 4 + r;
                const int col = bn0 + wc * (NT / 2) + j * 16 + l16;
                const size_t idx = (size_t)row * N + col;
                float v = acc[i][j][r];
                if (resid) v = (v * 0.7f + resid[idx] * 0.3f) * 1.3130643285972254f;
                if (Cb) Cb[idx] = f2bf(v);
                else    C[idx]  = v;
            }
}

// One-shot pixel-norm + relayout from bf16 qkv.
__global__ __launch_bounds__(256) void prep_qkv(const short* __restrict__ qkvb,
                                                const float* __restrict__ memkv,
                                                short* __restrict__ Qb,
                                                short* __restrict__ Kb,
                                                short* __restrict__ Vt) {
    __shared__ short Ls[64 * LDH];
    const int bh = blockIdx.x, bb = bh >> 4, h = bh & 15;
    const int tile = blockIdx.y;
    const int tid = threadIdx.x;
    const int r = tid >> 2, part = tid & 3;

    if (tile < 32) {
        const int tok = tile * 64 + r;
        const short* base = qkvb + ((size_t)(bb * 2048 + tok)) * 3072 + h * 64 + part * 16;
        float q[16], k[16], v[16];
        float ssq = 0.f, ssk = 0.f, ssv = 0.f;
        short8 a0 = *(const short8*)base,          a1 = *(const short8*)(base + 8);
        short8 b0 = *(const short8*)(base + 1024), b1 = *(const short8*)(base + 1032);
        short8 c0 = *(const short8*)(base + 2048), c1 = *(const short8*)(base + 2056);
        #pragma unroll
        for (int i = 0; i < 8; i++) {
            q[i] = bf2f(a0[i]); q[8+i] = bf2f(a1[i]);
            k[i] = bf2f(b0[i]); k[8+i] = bf2f(b1[i]);
            v[i] = bf2f(c0[i]); v[8+i] = bf2f(c1[i]);
        }
        #pragma unroll
        for (int i = 0; i < 16; i++) { ssq += q[i]*q[i]; ssk += k[i]*k[i]; ssv += v[i]*v[i]; }
        ssq += __shfl_xor(ssq, 1); ssq += __shfl_xor(ssq, 2);
        ssk += __shfl_xor(ssk, 1); ssk += __shfl_xor(ssk, 2);
        ssv += __shfl_xor(ssv, 1); ssv += __shfl_xor(ssv, 2);
        const float fq = LOG2E / fmaxf(sqrtf(ssq), EPSN);
        const float fk = 8.0f / fmaxf(sqrtf(ssk), EPSN);
        const float fv = 8.0f / fmaxf(sqrtf(ssv), EPSN);
        short8 oq, ok, oq1, ok1;
        #pragma unroll
        for (int i = 0; i < 8; i++) { oq[i] = f2bf(q[i] * fq); ok[i] = f2bf(k[i] * fk); }
        #pragma unroll
        for (int i = 0; i < 8; i++) { oq1[i] = f2bf(q[8+i] * fq); ok1[i] = f2bf(k[8+i] * fk); }
        short* qd = Qb + ((size_t)bh * 2048 + tok) * 64 + part * 16;
        *(short8*)qd = oq; *(short8*)(qd + 8) = oq1;
        short* kd = Kb + ((size_t)bh * NKEY + 4 + tok) * 64 + part * 16;
        *(short8*)kd = ok; *(short8*)(kd + 8) = ok1;
        #pragma unroll
        for (int i = 0; i < 16; i++) Ls[r * LDH + part * 16 + i] = f2bf(v[i] * fv);
        __syncthreads();
        short4v o[4];
        #pragma unroll
        for (int j = 0; j < 16; j++) o[j >> 2][j & 3] = Ls[(part * 16 + j) * LDH + r];
        short* vd = Vt + ((size_t)bh * 64 + r) * NKEY + 4 + tile * 64 + part * 16;
        #pragma unroll
        for (int j = 0; j < 4; j++) *(short4v*)(vd + j * 4) = o[j];
    } else {
        if (r < 4) {
            const float* pk = memkv + (size_t)(h * 4 + r) * 64 + part * 16;
            const float* pv = memkv + (size_t)((16 + h) * 4 + r) * 64 + part * 16;
            float k[16], v[16]; float ssk = 0.f, ssv = 0.f;
            #pragma unroll
            for (int i = 0; i < 16; i += 4) {
                float4 a = *(const float4*)(pk + i);
                float4 b = *(const float4*)(pv + i);
                k[i]=a.x; k[i+1]=a.y; k[i+2]=a.z; k[i+3]=a.w;
                v[i]=b.x; v[i+1]=b.y; v[i+2]=b.z; v[i+3]=b.w;
                ssk += a.x*a.x + a.y*a.y + a.z*a.z + a.w*a.w;
                ssv += b.x*b.x + b.y*b.y + b.z*b.z + b.w*b.w;
            }
            ssk += __shfl_xor(ssk, 1); ssk += __shfl_xor(ssk, 2);
            ssv += __shfl_xor(ssv, 1); ssv += __shfl_xor(ssv, 2);
            const float fk = 8.0f / fmaxf(sqrtf(ssk), EPSN);
            const float fv = 8.0f / fmaxf(sqrtf(ssv), EPSN);
            short* kd = Kb + ((size_t)bh * NKEY + r) * 64 + part * 16;
            #pragma unroll
            for (int i = 0; i < 16; i++) kd[i] = f2bf(k[i] * fk);
            #pragma unroll
            for (int i = 0; i < 16; i++)
                Vt[((size_t)bh * 64 + part * 16 + i) * NKEY + r] = f2bf(v[i] * fv);
        }
        for (int p = tid; p < 480; p += 256)
            *(short8*)(Kb + ((size_t)bh * NKEY + 2052) * 64 + p * 8) = (short8){0,0,0,0,0,0,0,0};
        for (int p = tid; p < 960; p += 256) {
            int row = p / 15, c = p % 15;
            *(short4v*)(Vt + ((size_t)bh * 64 + row) * NKEY + 2052 + c * 4) = (short4v){0,0,0,0};
        }
    }
}

// Flash attention, fixed-shift exp2 softmax. 512 threads = 8 waves, 128 q-rows
// per block (16/wave); one shared K/V tile per iteration serves all 8 waves.
__global__ __launch_bounds__(512) void attn_mfma(const short* __restrict__ Qb,
                                                 const short* __restrict__ Kb,
                                                 const short* __restrict__ Vt,
                                                 short* __restrict__ out) {
    const int bh = blockIdx.x;
    const int q0 = blockIdx.y * 128;
    const int tid = threadIdx.x;
    const int wave = tid >> 6;
    const int lane = tid & 63;
    const int l16 = lane & 15;
    const int quad = lane >> 4;

    __shared__ __align__(16) short Ks[64 * LDH];
    __shared__ __align__(16) short Vs[64 * LDH];
    __shared__ __align__(16) short Ps[8][16 * LDH];

    const short* qp = Qb + ((size_t)bh * 2048 + q0 + wave * 16 + l16) * 64 + quad * 8;
    short8 aQ0 = *(const short8*)qp;
    short8 aQ1 = *(const short8*)(qp + 32);

    floatx4 O[4];
    #pragma unroll
    for (int t = 0; t < 4; t++) O[t] = (floatx4){0.f, 0.f, 0.f, 0.f};
    float lp[4] = {0.f, 0.f, 0.f, 0.f};

    const int srow = tid >> 3, sch = tid & 7;   // 512 thr: one b128 K + one b128 V each
    for (int tile = 0; tile < 33; tile++) {
        __syncthreads();
        {
            short8 kv = *(const short8*)(Kb + ((size_t)bh * NKEY + tile * 64 + srow) * 64 + sch * 8);
            *(short8*)&Ks[srow * LDH + sch * 8] = kv;
            short8 vv = *(const short8*)(Vt + ((size_t)bh * 64 + srow) * NKEY + tile * 64 + sch * 8);
            *(short8*)&Vs[srow * LDH + sch * 8] = vv;
        }
        __syncthreads();

        floatx4 S[4];
        #pragma unroll
        for (int t = 0; t < 4; t++) {
            const short* pb = &Ks[(t * 16 + l16) * LDH + quad * 8];
            short8 b0 = *(const short8*)pb;
            short8 b1 = *(const short8*)(pb + 32);
            floatx4 s = (floatx4){-12.f, -12.f, -12.f, -12.f};
            s = __builtin_amdgcn_mfma_f32_16x16x32_bf16(aQ0, b0, s, 0, 0, 0);
            s = __builtin_amdgcn_mfma_f32_16x16x32_bf16(aQ1, b1, s, 0, 0, 0);
            S[t] = s;
        }
        if (tile == 32) {
            #pragma unroll
            for (int t = 0; t < 4; t++)
                if (t * 16 + l16 >= 4) { S[t][0] = S[t][1] = S[t][2] = S[t][3] = -1e30f; }
        }
        short* pp = Ps[wave];
        #pragma unroll
        for (int t = 0; t < 4; t++) {
            #pragma unroll
            for (int i = 0; i < 4; i++) {
                float p = __builtin_amdgcn_exp2f(S[t][i]);
                lp[i] += p;
                pp[(quad * 4 + i) * LDH + t * 16 + l16] = f2bf_fast(p);
            }
        }
        short8 aP0, aP1;
        {
            const short* pa = &pp[l16 * LDH + quad * 8];
            aP0 = *(const short8*)pa;
            aP1 = *(const short8*)(pa + 32);
        }
        #pragma unroll
        for (int t = 0; t < 4; t++) {
            const short* pv2 = &Vs[(t * 16 + l16) * LDH + quad * 8];
            short8 b0 = *(const short8*)pv2;
            short8 b1 = *(const short8*)(pv2 + 32);
            O[t] = __builtin_amdgcn_mfma_f32_16x16x32_bf16(aP0, b0, O[t], 0, 0, 0);
            O[t] = __builtin_amdgcn_mfma_f32_16x16x32_bf16(aP1, b1, O[t], 0, 0, 0);
        }
    }

    const int bb = bh >> 4, h = bh & 15;
    #pragma unroll
    for (int i = 0; i < 4; i++) {
        float s = lp[i];
        s += __shfl_xor(s, 1); s += __shfl_xor(s, 2);
        s += __shfl_xor(s, 4); s += __shfl_xor(s, 8);
        const float inv = 1.0f / s;
        const int qrow = q0 + wave * 16 + quad * 4 + i;
        const size_t base = ((size_t)(bb * 2048 + qrow)) * 1024 + h * 64 + l16;
        #pragma unroll
        for (int t = 0; t < 4; t++) out[base + t * 16] = f2bf(O[t][i] * inv);
    }
}

extern "C" void kernel_launch(void* const* d_in, const int* in_sizes, int n_in,
                              void* d_out, int out_size, void* d_ws, size_t ws_size,
                              hipStream_t stream) {
    const float* x      = (const float*)d_in[0];
    const float* w_qkv  = (const float*)d_in[1];
    const float* w_out  = (const float*)d_in[2];
    const float* mem_kv = (const float*)d_in[3];
    float* out = (float*)d_out;

    char* ws = (char*)d_ws;
    short* wnqkv_b = (short*)(ws);                    // 6 MB
    short* wnout_b = (short*)(ws + (6u << 20));       // 2 MB
    short* xb      = (short*)(ws + (8u << 20));       // 8 MB
    short* qkvb    = (short*)(ws + (16u << 20));      // 24 MB
    short* attnb   = (short*)(ws + (40u << 20));      // 8 MB
    short* Qb      = (short*)(ws + (48u << 20));      // 8 MB
    short* Kb      = (short*)(ws + (56u << 20));      // 8.25 MB
    short* Vt      = (short*)(ws + (65u << 20));      // 8.25 MB (total ~74 MB)

    cast_bf16<<<4096, 256, 0, stream>>>(x, xb);
    norm_rows<<<3072, 256, 0, stream>>>(w_qkv, wnqkv_b, 1024);
    norm_rows<<<1024, 256, 0, stream>>>(w_out, wnout_b, 1024);

    // qkvb = xb @ wnqkv^T : M=4096, N=3072, K=1024 (bf16 out)
    gemm_mfma<128, 128><<<dim3(3072 / 128, 4096 / 128), 256, 0, stream>>>(
        xb, wnqkv_b, nullptr, qkvb, 4096, 3072, 1024, nullptr);

    prep_qkv<<<dim3(32, 33), 256, 0, stream>>>(qkvb, mem_kv, Qb, Kb, Vt);

    attn_mfma<<<dim3(32, 16), 512, 0, stream>>>(Qb, Kb, Vt, attnb);

    // out = attnb @ wnout^T + residual : M=4096, N=1024, K=1024 (fp32 out)
    gemm_mfma<64, 64><<<dim3(1024 / 64, 4096 / 64), 256, 0, stream>>>(
        attnb, wnout_b, out, nullptr, 4096, 1024, 1024, x);
}

// Round 7
// 215.946 us; speedup vs baseline: 17.8250x; 1.0673x over previous
//
#include <hip/hip_runtime.h>
#include <hip/hip_bf16.h>
#include <math.h>

// MP Attention: b=2, n=2048, dim=1024, h=16, d=64.
//  1. prep_inputs (fused): xb=bf16(x) | wn=bf16(w/(max(||row||,eps)*32)) for both
//     weights | memkv rows + zero pads into Kb/Vt.
//  2. gemm_qkv:  pipelined 128x128 bf16 MFMA GEMM, pixel-norm EPILOGUE writes
//     Qb (x log2e), Kb rows 4.., Vt transposed — no qkv intermediate.
//  3. attn_mfma: flash attention, async16 double-buffered K/V staging
//     (global_load_lds, half-row LDS layout), fixed-shift exp2 softmax.
//  4. gemm_mfma<128,64>: out = attnb @ wn_out^T + MP residual.

#define EPSN 1e-4f
#define LDH 72
#define NKEY 2112
#define LOG2E 1.4426950408889634f

typedef __attribute__((ext_vector_type(8))) short short8;
typedef __attribute__((ext_vector_type(4))) short short4v;
typedef __attribute__((ext_vector_type(4))) float floatx4;

typedef __attribute__((address_space(1))) const void g_void;
typedef __attribute__((address_space(3))) void lds_void;

__device__ __forceinline__ void async16(void* lds, const void* g) {
    __builtin_amdgcn_global_load_lds((g_void*)g, (lds_void*)lds, 16, 0, 0);
}

__device__ __forceinline__ short f2bf(float f) {   // RNE
    union { float f; unsigned u; } c{f};
    unsigned r = (c.u + 0x7FFF + ((c.u >> 16) & 1)) >> 16;
    return (short)r;
}
__device__ __forceinline__ short f2bf_fast(float f) {  // round-half-up (P in [0,1])
    union { float f; unsigned u; } c{f};
    return (short)((c.u + 0x8000) >> 16);
}

// Fused setup: cast x, normalize both weight matrices, memkv rows + zero pads.
__global__ __launch_bounds__(256) void prep_inputs(const float* __restrict__ x,
                                                   const float* __restrict__ w_qkv,
                                                   const float* __restrict__ w_out,
                                                   const float* __restrict__ memkv,
                                                   short* __restrict__ xb,
                                                   short* __restrict__ wnqkv,
                                                   short* __restrict__ wnout,
                                                   short* __restrict__ Kb,
                                                   short* __restrict__ Vt) {
    const int bid = blockIdx.x, tid = threadIdx.x;
    if (bid < 4096) {                       // cast x -> bf16
        int i = bid * 1024 + tid * 4;
        float4 v = *(const float4*)(x + i);
        short4v s = {f2bf(v.x), f2bf(v.y), f2bf(v.z), f2bf(v.w)};
        *(short4v*)(xb + i) = s;
        return;
    }
    if (bid < 8192) {                       // weight row norms
        const float* w; short* wn; int r;
        if (bid < 7168) { w = w_qkv; wn = wnqkv; r = bid - 4096; }
        else            { w = w_out; wn = wnout; r = bid - 7168; }
        __shared__ float red[256];
        const float* row = w + (size_t)r * 1024;
        float ss = 0.f;
        for (int c = tid; c < 1024; c += 256) { float v = row[c]; ss += v * v; }
        red[tid] = ss;
        __syncthreads();
        for (int s = 128; s > 0; s >>= 1) {
            if (tid < s) red[tid] += red[tid + s];
            __syncthreads();
        }
        float f = 1.0f / (fmaxf(sqrtf(red[0]), EPSN) * 32.0f);
        for (int c = tid; c < 1024; c += 256) wn[(size_t)r * 1024 + c] = f2bf(row[c] * f);
        return;
    }
    // memkv rows 0..3 of Kb / cols 0..3 of Vt, plus zero pads. One block per bh.
    const int bh = bid - 8192, h = bh & 15;
    const int r = tid >> 2, part = tid & 3;
    if (r < 4) {
        const float* pk = memkv + (size_t)(h * 4 + r) * 64 + part * 16;
        const float* pv = memkv + (size_t)((16 + h) * 4 + r) * 64 + part * 16;
        float k[16], v[16]; float ssk = 0.f, ssv = 0.f;
        #pragma unroll
        for (int i = 0; i < 16; i += 4) {
            float4 a = *(const float4*)(pk + i);
            float4 b = *(const float4*)(pv + i);
            k[i]=a.x; k[i+1]=a.y; k[i+2]=a.z; k[i+3]=a.w;
            v[i]=b.x; v[i+1]=b.y; v[i+2]=b.z; v[i+3]=b.w;
            ssk += a.x*a.x + a.y*a.y + a.z*a.z + a.w*a.w;
            ssv += b.x*b.x + b.y*b.y + b.z*b.z + b.w*b.w;
        }
        ssk += __shfl_xor(ssk, 1); ssk += __shfl_xor(ssk, 2);
        ssv += __shfl_xor(ssv, 1); ssv += __shfl_xor(ssv, 2);
        const float fk = 8.0f / fmaxf(sqrtf(ssk), EPSN);
        const float fv = 8.0f / fmaxf(sqrtf(ssv), EPSN);
        short* kd = Kb + ((size_t)bh * NKEY + r) * 64 + part * 16;
        #pragma unroll
        for (int i = 0; i < 16; i++) kd[i] = f2bf(k[i] * fk);
        #pragma unroll
        for (int i = 0; i < 16; i++)
            Vt[((size_t)bh * 64 + part * 16 + i) * NKEY + r] = f2bf(v[i] * fv);
    }
    for (int p = tid; p < 480; p += 256)
        *(short8*)(Kb + ((size_t)bh * NKEY + 2052) * 64 + p * 8) = (short8){0,0,0,0,0,0,0,0};
    for (int p = tid; p < 960; p += 256) {
        int row = p / 15, c = p % 15;
        *(short4v*)(Vt + ((size_t)bh * 64 + row) * NKEY + 2052 + c * 4) = (short4v){0,0,0,0};
    }
}

// qkv projection GEMM (M=4096, N=3072, K=1024) with fused pixel-norm epilogue.
// Each wave's 64-col half is one head of q, k, or v -> row-norm is an in-wave
// reduction over the accumulator; writes Qb/Kb/Vt directly (no qkv intermediate).
__global__ __launch_bounds__(256) void gemm_qkv(const short* __restrict__ A,
                                                const short* __restrict__ B,
                                                short* __restrict__ Qb,
                                                short* __restrict__ Kb,
                                                short* __restrict__ Vt) {
    constexpr int K = 1024;
    __shared__ __align__(16) short As[2][128 * 32];
    __shared__ __align__(16) short Bs[2][128 * 32];
    const int tid = threadIdx.x;
    const int wv = tid >> 6, lane = tid & 63;
    const int l16 = lane & 15, quad = lane >> 4;
    const int wr = wv >> 1, wc = wv & 1;
    const int bm0 = blockIdx.y * 128, bn0 = blockIdx.x * 128;
    const int grow = lane >> 2;
    const int gk = (lane & 3) * 8;

    floatx4 acc[4][4];
    #pragma unroll
    for (int i = 0; i < 4; i++)
        #pragma unroll
        for (int j = 0; j < 4; j++) acc[i][j] = (floatx4){0.f, 0.f, 0.f, 0.f};

    const short* Abase = A + (size_t)(bm0 + wv * 32 + grow) * K + gk;
    const short* Bbase = B + (size_t)(bn0 + wv * 32 + grow) * K + gk;

    #pragma unroll
    for (int j = 0; j < 2; j++) {
        async16(&As[0][(wv * 32 + j * 16) * 32], Abase + (size_t)(j * 16) * K);
        async16(&Bs[0][(wv * 32 + j * 16) * 32], Bbase + (size_t)(j * 16) * K);
    }
    const int NKI = K >> 5;
    for (int ki = 0; ki < NKI; ki++) {
        const int cur = ki & 1;
        if (ki + 1 < NKI) {
            const int nxt = cur ^ 1;
            const int off = (ki + 1) * 32;
            #pragma unroll
            for (int j = 0; j < 2; j++) {
                async16(&As[nxt][(wv * 32 + j * 16) * 32], Abase + (size_t)(j * 16) * K + off);
                async16(&Bs[nxt][(wv * 32 + j * 16) * 32], Bbase + (size_t)(j * 16) * K + off);
            }
            asm volatile("s_waitcnt vmcnt(4)" ::: "memory");
        } else {
            asm volatile("s_waitcnt vmcnt(0)" ::: "memory");
        }
        asm volatile("s_barrier" ::: "memory");
        short8 aA[4], bB[4];
        #pragma unroll
        for (int i = 0; i < 4; i++)
            aA[i] = *(const short8*)&As[cur][(wr * 64 + i * 16 + l16) * 32 + quad * 8];
        #pragma unroll
        for (int j = 0; j < 4; j++)
            bB[j] = *(const short8*)&Bs[cur][(wc * 64 + j * 16 + l16) * 32 + quad * 8];
        #pragma unroll
        for (int i = 0; i < 4; i++)
            #pragma unroll
            for (int j = 0; j < 4; j++)
                acc[i][j] = __builtin_amdgcn_mfma_f32_16x16x32_bf16(aA[i], bB[j], acc[i][j], 0, 0, 0);
        asm volatile("s_barrier" ::: "memory");
    }

    // ---- pixel-norm epilogue: this wave's 64 cols = one head of q/k/v
    const int colbase = bn0 + wc * 64;
    const int which = colbase >> 10;          // 0=q 1=k 2=v
    const int h = (colbase >> 6) & 15;
    float sc[4][4];
    #pragma unroll
    for (int i = 0; i < 4; i++)
        #pragma unroll
        for (int r = 0; r < 4; r++) {
            float ss = 0.f;
            #pragma unroll
            for (int j = 0; j < 4; j++) ss += acc[i][j][r] * acc[i][j][r];
            ss += __shfl_xor(ss, 1); ss += __shfl_xor(ss, 2);
            ss += __shfl_xor(ss, 4); ss += __shfl_xor(ss, 8);
            const float num = (which == 0) ? LOG2E : 8.0f;   // q: *8 cancels 1/8 scale, xlog2e
            sc[i][r] = num / fmaxf(sqrtf(ss), EPSN);
        }
    if (which == 2) {
        #pragma unroll
        for (int i = 0; i < 4; i++) {
            const int row0 = bm0 + wr * 64 + i * 16 + quad * 4;
            const int bh = (row0 >> 11) * 16 + h;
            const int tok0 = row0 & 2047;
            #pragma unroll
            for (int j = 0; j < 4; j++) {
                const int d = j * 16 + l16;
                short4v o = {f2bf(acc[i][j][0] * sc[i][0]), f2bf(acc[i][j][1] * sc[i][1]),
                             f2bf(acc[i][j][2] * sc[i][2]), f2bf(acc[i][j][3] * sc[i][3])};
                *(short4v*)(Vt + ((size_t)bh * 64 + d) * NKEY + 4 + tok0) = o;
            }
        }
    } else {
        #pragma unroll
        for (int i = 0; i < 4; i++)
            #pragma unroll
            for (int r = 0; r < 4; r++) {
                const int row = bm0 + wr * 64 + i * 16 + quad * 4 + r;
                const int bh = (row >> 11) * 16 + h;
                const int tok = row & 2047;
                const size_t base = (which == 0) ? ((size_t)bh * 2048 + tok) * 64
                                                 : ((size_t)bh * NKEY + 4 + tok) * 64;
                short* dst = (which == 0) ? Qb : Kb;
                #pragma unroll
                for (int j = 0; j < 4; j++)
                    dst[base + j * 16 + l16] = f2bf(acc[i][j][r] * sc[i][r]);
            }
    }
}

// out-projection GEMM, pipelined, fp32 out + MP residual.
template<int MT, int NT>
__global__ __launch_bounds__(256) void gemm_mfma(const short* __restrict__ A,
                                                 const short* __restrict__ B,
                                                 float* __restrict__ C,
                                                 int M, int N, int K,
                                                 const float* __restrict__ resid) {
    constexpr int FI = MT / 32;
    constexpr int FJ = NT / 32;
    constexpr int nA = MT / 64;
    constexpr int nB = NT / 64;
    __shared__ __align__(16) short As[2][MT * 32];
    __shared__ __align__(16) short Bs[2][NT * 32];
    const int tid = threadIdx.x;
    const int wv = tid >> 6, lane = tid & 63;
    const int l16 = lane & 15, quad = lane >> 4;
    const int wr = wv >> 1, wc = wv & 1;
    const int bm0 = blockIdx.y * MT, bn0 = blockIdx.x * NT;
    const int grow = lane >> 2;
    const int gk = (lane & 3) * 8;

    floatx4 acc[FI][FJ];
    #pragma unroll
    for (int i = 0; i < FI; i++)
        #pragma unroll
        for (int j = 0; j < FJ; j++) acc[i][j] = (floatx4){0.f, 0.f, 0.f, 0.f};

    const short* Abase = A + (size_t)(bm0 + wv * (MT / 4) + grow) * K + gk;
    const short* Bbase = B + (size_t)(bn0 + wv * (NT / 4) + grow) * K + gk;

    #pragma unroll
    for (int j = 0; j < nA; j++)
        async16(&As[0][(wv * (MT / 4) + j * 16) * 32], Abase + (size_t)(j * 16) * K);
    #pragma unroll
    for (int j = 0; j < nB; j++)
        async16(&Bs[0][(wv * (NT / 4) + j * 16) * 32], Bbase + (size_t)(j * 16) * K);

    const int NKI = K >> 5;
    for (int ki = 0; ki < NKI; ki++) {
        const int cur = ki & 1;
        if (ki + 1 < NKI) {
            const int nxt = cur ^ 1;
            const int off = (ki + 1) * 32;
            #pragma unroll
            for (int j = 0; j < nA; j++)
                async16(&As[nxt][(wv * (MT / 4) + j * 16) * 32], Abase + (size_t)(j * 16) * K + off);
            #pragma unroll
            for (int j = 0; j < nB; j++)
                async16(&Bs[nxt][(wv * (NT / 4) + j * 16) * 32], Bbase + (size_t)(j * 16) * K + off);
            if constexpr (nA + nB == 4)      asm volatile("s_waitcnt vmcnt(4)" ::: "memory");
            else if constexpr (nA + nB == 3) asm volatile("s_waitcnt vmcnt(3)" ::: "memory");
            else                             asm volatile("s_waitcnt vmcnt(2)" ::: "memory");
        } else {
            asm volatile("s_waitcnt vmcnt(0)" ::: "memory");
        }
        asm volatile("s_barrier" ::: "memory");
        short8 aA[FI], bB[FJ];
        #pragma unroll
        for (int i = 0; i < FI; i++)
            aA[i] = *(const short8*)&As[cur][(wr * (MT / 2) + i * 16 + l16) * 32 + quad * 8];
        #pragma unroll
        for (int j = 0; j < FJ; j++)
            bB[j] = *(const short8*)&Bs[cur][(wc * (NT / 2) + j * 16 + l16) * 32 + quad * 8];
        #pragma unroll
        for (int i = 0; i < FI; i++)
            #pragma unroll
            for (int j = 0; j < FJ; j++)
                acc[i][j] = __builtin_amdgcn_mfma_f32_16x16x32_bf16(aA[i], bB[j], acc[i][j], 0, 0, 0);
        asm volatile("s_barrier" ::: "memory");
    }
    #pragma unroll
    for (int i = 0; i < FI; i++)
        #pragma unroll
        for (int j = 0; j < FJ; j++)
            #pragma unroll
            for (int r = 0; r < 4; r++) {
                const int row = bm0 + wr * (MT / 2) + i * 16 + quad * 4 + r;
                const int col = bn0 + wc * (NT / 2) + j * 16 + l16;
                const size_t idx = (size_t)row * N + col;
                float v = acc[i][j][r];
                if (resid) v = (v * 0.7f + resid[idx] * 0.3f) * 1.3130643285972254f;
                C[idx] = v;
            }
}

// Flash attention: 512 thr = 8 waves, 128 q-rows/block; async16 double-buffered
// K/V staging in half-row (32-short) LDS layout; fixed-shift exp2 softmax.
__global__ __launch_bounds__(512) void attn_mfma(const short* __restrict__ Qb,
                                                 const short* __restrict__ Kb,
                                                 const short* __restrict__ Vt,
                                                 short* __restrict__ out) {
    const int bh = blockIdx.x;
    const int q0 = blockIdx.y * 128;
    const int tid = threadIdx.x;
    const int wave = tid >> 6, lane = tid & 63;
    const int l16 = lane & 15, quad = lane >> 4;

    __shared__ __align__(16) short Ks2[2][2][64 * 32];  // [buf][d-half][key][32]
    __shared__ __align__(16) short Vs2[2][2][64 * 32];  // [buf][key-half][d][32]
    __shared__ __align__(16) short Ps[8][16 * LDH];

    const short* qp = Qb + ((size_t)bh * 2048 + q0 + wave * 16 + l16) * 64 + quad * 8;
    short8 aQ0 = *(const short8*)qp;
    short8 aQ1 = *(const short8*)(qp + 32);
    asm volatile("s_waitcnt vmcnt(0)" ::: "memory");  // Q resident before async pipeline

    const int grow = lane >> 2, gsub = (lane & 3) * 8;
    const int u0 = wave * 2;
    auto issue = [&](int tile, int buf) {
        #pragma unroll
        for (int s = 0; s < 2; s++) {
            const int u = u0 + s;          // 0..15, wave-uniform
            const int hh = (u >> 2) & 1;
            const int L = u & 3;
            const int rr = L * 16 + grow;
            const int cc = hh * 32 + gsub;
            if (u < 8)
                async16(&Ks2[buf][hh][L * 512],
                        Kb + ((size_t)bh * NKEY + tile * 64 + rr) * 64 + cc);
            else
                async16(&Vs2[buf][hh][L * 512],
                        Vt + ((size_t)bh * 64 + rr) * NKEY + tile * 64 + cc);
        }
    };

    floatx4 O[4];
    #pragma unroll
    for (int t = 0; t < 4; t++) O[t] = (floatx4){0.f, 0.f, 0.f, 0.f};
    float lp[4] = {0.f, 0.f, 0.f, 0.f};

    issue(0, 0);
    for (int tile = 0; tile < 33; tile++) {
        const int cur = tile & 1;
        if (tile < 32) {
            issue(tile + 1, cur ^ 1);
            asm volatile("s_waitcnt vmcnt(2)" ::: "memory");
        } else {
            asm volatile("s_waitcnt vmcnt(0)" ::: "memory");
        }
        asm volatile("s_barrier" ::: "memory");

        floatx4 S[4];
        #pragma unroll
        for (int t = 0; t < 4; t++) {
            short8 b0 = *(const short8*)&Ks2[cur][0][(t * 16 + l16) * 32 + quad * 8];
            short8 b1 = *(const short8*)&Ks2[cur][1][(t * 16 + l16) * 32 + quad * 8];
            floatx4 s = (floatx4){-12.f, -12.f, -12.f, -12.f};
            s = __builtin_amdgcn_mfma_f32_16x16x32_bf16(aQ0, b0, s, 0, 0, 0);
            s = __builtin_amdgcn_mfma_f32_16x16x32_bf16(aQ1, b1, s, 0, 0, 0);
            S[t] = s;
        }
        if (tile == 32) {   // keys 2052..2111 are padding
            #pragma unroll
            for (int t = 0; t < 4; t++)
                if (t * 16 + l16 >= 4) { S[t][0] = S[t][1] = S[t][2] = S[t][3] = -1e30f; }
        }
        short* pp = Ps[wave];
        #pragma unroll
        for (int t = 0; t < 4; t++) {
            #pragma unroll
            for (int i = 0; i < 4; i++) {
                float p = __builtin_amdgcn_exp2f(S[t][i]);
                lp[i] += p;
                pp[(quad * 4 + i) * LDH + t * 16 + l16] = f2bf_fast(p);
            }
        }
        short8 aP0, aP1;
        {
            const short* pa = &pp[l16 * LDH + quad * 8];
            aP0 = *(const short8*)pa;
            aP1 = *(const short8*)(pa + 32);
        }
        #pragma unroll
        for (int t = 0; t < 4; t++) {
            short8 b0 = *(const short8*)&Vs2[cur][0][(t * 16 + l16) * 32 + quad * 8];
            short8 b1 = *(const short8*)&Vs2[cur][1][(t * 16 + l16) * 32 + quad * 8];
            O[t] = __builtin_amdgcn_mfma_f32_16x16x32_bf16(aP0, b0, O[t], 0, 0, 0);
            O[t] = __builtin_amdgcn_mfma_f32_16x16x32_bf16(aP1, b1, O[t], 0, 0, 0);
        }
        asm volatile("s_barrier" ::: "memory");
    }

    const int bb = bh >> 4, h = bh & 15;
    #pragma unroll
    for (int i = 0; i < 4; i++) {
        float s = lp[i];
        s += __shfl_xor(s, 1); s += __shfl_xor(s, 2);
        s += __shfl_xor(s, 4); s += __shfl_xor(s, 8);
        const float inv = 1.0f / s;
        const int qrow = q0 + wave * 16 + quad * 4 + i;
        const size_t base = ((size_t)(bb * 2048 + qrow)) * 1024 + h * 64 + l16;
        #pragma unroll
        for (int t = 0; t < 4; t++) out[base + t * 16] = f2bf(O[t][i] * inv);
    }
}

extern "C" void kernel_launch(void* const* d_in, const int* in_sizes, int n_in,
                              void* d_out, int out_size, void* d_ws, size_t ws_size,
                              hipStream_t stream) {
    const float* x      = (const float*)d_in[0];
    const float* w_qkv  = (const float*)d_in[1];
    const float* w_out  = (const float*)d_in[2];
    const float* mem_kv = (const float*)d_in[3];
    float* out = (float*)d_out;

    char* ws = (char*)d_ws;
    short* wnqkv_b = (short*)(ws);                    // 6 MB
    short* wnout_b = (short*)(ws + (6u << 20));       // 2 MB
    short* xb      = (short*)(ws + (8u << 20));       // 8 MB
    short* Qb      = (short*)(ws + (16u << 20));      // 8 MB
    short* Kb      = (short*)(ws + (24u << 20));      // 8.25 MB
    short* Vt      = (short*)(ws + (33u << 20));      // 8.25 MB
    short* attnb   = (short*)(ws + (42u << 20));      // 8 MB  (total ~50 MB)

    prep_inputs<<<8224, 256, 0, stream>>>(x, w_qkv, w_out, mem_kv,
                                          xb, wnqkv_b, wnout_b, Kb, Vt);

    gemm_qkv<<<dim3(3072 / 128, 4096 / 128), 256, 0, stream>>>(
        xb, wnqkv_b, Qb, Kb, Vt);

    attn_mfma<<<dim3(32, 16), 512, 0, stream>>>(Qb, Kb, Vt, attnb);

    gemm_mfma<128, 64><<<dim3(1024 / 64, 4096 / 128), 256, 0, stream>>>(
        attnb, wnout_b, out, 4096, 1024, 1024, x);
}

// Round 8
// 212.465 us; speedup vs baseline: 18.1171x; 1.0164x over previous
//
#include <hip/hip_runtime.h>
#include <hip/hip_bf16.h>
#include <math.h>

// MP Attention: b=2, n=2048, dim=1024, h=16, d=64.
//  1. prep_inputs: xb=bf16(x) | wn=bf16(w/(max(||row||,eps)*32)) | memkv + pads.
//  2. gemm_qkv:  pipelined 128x128 bf16 MFMA GEMM + pixel-norm epilogue ->
//     Qb (x log2e), Kb rows 4.., Vt transposed.
//  3. attn_mfma: flash attention, TRANSPOSED schedule: S^T = K·Q^T (A=K,B=Q),
//     O^T = V^T·P^T. 4 waves x 32 q-rows; P^T via wave-private LDS (b64 w / b128 r,
//     no barrier); fixed-shift exp2 softmax, denominator deferred to epilogue.
//  4. gemm_mfma<128,64>: out = attnb @ wn_out^T + MP residual.

#define EPSN 1e-4f
#define NKEY 2112
#define LOG2E 1.4426950408889634f

typedef __attribute__((ext_vector_type(8))) short short8;
typedef __attribute__((ext_vector_type(4))) short short4v;
typedef __attribute__((ext_vector_type(4))) float floatx4;

typedef __attribute__((address_space(1))) const void g_void;
typedef __attribute__((address_space(3))) void lds_void;

__device__ __forceinline__ void async16(void* lds, const void* g) {
    __builtin_amdgcn_global_load_lds((g_void*)g, (lds_void*)lds, 16, 0, 0);
}

__device__ __forceinline__ short f2bf(float f) {   // RNE
    union { float f; unsigned u; } c{f};
    unsigned r = (c.u + 0x7FFF + ((c.u >> 16) & 1)) >> 16;
    return (short)r;
}
__device__ __forceinline__ short f2bf_fast(float f) {  // round-half-up (P in [0,1])
    union { float f; unsigned u; } c{f};
    return (short)((c.u + 0x8000) >> 16);
}

// Fused setup: cast x, normalize both weight matrices, memkv rows + zero pads.
__global__ __launch_bounds__(256) void prep_inputs(const float* __restrict__ x,
                                                   const float* __restrict__ w_qkv,
                                                   const float* __restrict__ w_out,
                                                   const float* __restrict__ memkv,
                                                   short* __restrict__ xb,
                                                   short* __restrict__ wnqkv,
                                                   short* __restrict__ wnout,
                                                   short* __restrict__ Kb,
                                                   short* __restrict__ Vt) {
    const int bid = blockIdx.x, tid = threadIdx.x;
    if (bid < 4096) {                       // cast x -> bf16
        int i = bid * 1024 + tid * 4;
        float4 v = *(const float4*)(x + i);
        short4v s = {f2bf(v.x), f2bf(v.y), f2bf(v.z), f2bf(v.w)};
        *(short4v*)(xb + i) = s;
        return;
    }
    if (bid < 8192) {                       // weight row norms
        const float* w; short* wn; int r;
        if (bid < 7168) { w = w_qkv; wn = wnqkv; r = bid - 4096; }
        else            { w = w_out; wn = wnout; r = bid - 7168; }
        __shared__ float red[256];
        const float* row = w + (size_t)r * 1024;
        float ss = 0.f;
        for (int c = tid; c < 1024; c += 256) { float v = row[c]; ss += v * v; }
        red[tid] = ss;
        __syncthreads();
        for (int s = 128; s > 0; s >>= 1) {
            if (tid < s) red[tid] += red[tid + s];
            __syncthreads();
        }
        float f = 1.0f / (fmaxf(sqrtf(red[0]), EPSN) * 32.0f);
        for (int c = tid; c < 1024; c += 256) wn[(size_t)r * 1024 + c] = f2bf(row[c] * f);
        return;
    }
    // memkv rows 0..3 of Kb / cols 0..3 of Vt, plus zero pads. One block per bh.
    const int bh = bid - 8192, h = bh & 15;
    const int r = tid >> 2, part = tid & 3;
    if (r < 4) {
        const float* pk = memkv + (size_t)(h * 4 + r) * 64 + part * 16;
        const float* pv = memkv + (size_t)((16 + h) * 4 + r) * 64 + part * 16;
        float k[16], v[16]; float ssk = 0.f, ssv = 0.f;
        #pragma unroll
        for (int i = 0; i < 16; i += 4) {
            float4 a = *(const float4*)(pk + i);
            float4 b = *(const float4*)(pv + i);
            k[i]=a.x; k[i+1]=a.y; k[i+2]=a.z; k[i+3]=a.w;
            v[i]=b.x; v[i+1]=b.y; v[i+2]=b.z; v[i+3]=b.w;
            ssk += a.x*a.x + a.y*a.y + a.z*a.z + a.w*a.w;
            ssv += b.x*b.x + b.y*b.y + b.z*b.z + b.w*b.w;
        }
        ssk += __shfl_xor(ssk, 1); ssk += __shfl_xor(ssk, 2);
        ssv += __shfl_xor(ssv, 1); ssv += __shfl_xor(ssv, 2);
        const float fk = 8.0f / fmaxf(sqrtf(ssk), EPSN);
        const float fv = 8.0f / fmaxf(sqrtf(ssv), EPSN);
        short* kd = Kb + ((size_t)bh * NKEY + r) * 64 + part * 16;
        #pragma unroll
        for (int i = 0; i < 16; i++) kd[i] = f2bf(k[i] * fk);
        #pragma unroll
        for (int i = 0; i < 16; i++)
            Vt[((size_t)bh * 64 + part * 16 + i) * NKEY + r] = f2bf(v[i] * fv);
    }
    for (int p = tid; p < 480; p += 256)
        *(short8*)(Kb + ((size_t)bh * NKEY + 2052) * 64 + p * 8) = (short8){0,0,0,0,0,0,0,0};
    for (int p = tid; p < 960; p += 256) {
        int row = p / 15, c = p % 15;
        *(short4v*)(Vt + ((size_t)bh * 64 + row) * NKEY + 2052 + c * 4) = (short4v){0,0,0,0};
    }
}

// qkv projection GEMM (M=4096, N=3072, K=1024) with fused pixel-norm epilogue.
__global__ __launch_bounds__(256) void gemm_qkv(const short* __restrict__ A,
                                                const short* __restrict__ B,
                                                short* __restrict__ Qb,
                                                short* __restrict__ Kb,
                                                short* __restrict__ Vt) {
    constexpr int K = 1024;
    __shared__ __align__(16) short As[2][128 * 32];
    __shared__ __align__(16) short Bs[2][128 * 32];
    const int tid = threadIdx.x;
    const int wv = tid >> 6, lane = tid & 63;
    const int l16 = lane & 15, quad = lane >> 4;
    const int wr = wv >> 1, wc = wv & 1;
    const int bm0 = blockIdx.y * 128, bn0 = blockIdx.x * 128;
    const int grow = lane >> 2;
    const int gk = (lane & 3) * 8;

    floatx4 acc[4][4];
    #pragma unroll
    for (int i = 0; i < 4; i++)
        #pragma unroll
        for (int j = 0; j < 4; j++) acc[i][j] = (floatx4){0.f, 0.f, 0.f, 0.f};

    const short* Abase = A + (size_t)(bm0 + wv * 32 + grow) * K + gk;
    const short* Bbase = B + (size_t)(bn0 + wv * 32 + grow) * K + gk;

    #pragma unroll
    for (int j = 0; j < 2; j++) {
        async16(&As[0][(wv * 32 + j * 16) * 32], Abase + (size_t)(j * 16) * K);
        async16(&Bs[0][(wv * 32 + j * 16) * 32], Bbase + (size_t)(j * 16) * K);
    }
    const int NKI = K >> 5;
    for (int ki = 0; ki < NKI; ki++) {
        const int cur = ki & 1;
        if (ki + 1 < NKI) {
            const int nxt = cur ^ 1;
            const int off = (ki + 1) * 32;
            #pragma unroll
            for (int j = 0; j < 2; j++) {
                async16(&As[nxt][(wv * 32 + j * 16) * 32], Abase + (size_t)(j * 16) * K + off);
                async16(&Bs[nxt][(wv * 32 + j * 16) * 32], Bbase + (size_t)(j * 16) * K + off);
            }
            asm volatile("s_waitcnt vmcnt(4)" ::: "memory");
        } else {
            asm volatile("s_waitcnt vmcnt(0)" ::: "memory");
        }
        asm volatile("s_barrier" ::: "memory");
        short8 aA[4], bB[4];
        #pragma unroll
        for (int i = 0; i < 4; i++)
            aA[i] = *(const short8*)&As[cur][(wr * 64 + i * 16 + l16) * 32 + quad * 8];
        #pragma unroll
        for (int j = 0; j < 4; j++)
            bB[j] = *(const short8*)&Bs[cur][(wc * 64 + j * 16 + l16) * 32 + quad * 8];
        #pragma unroll
        for (int i = 0; i < 4; i++)
            #pragma unroll
            for (int j = 0; j < 4; j++)
                acc[i][j] = __builtin_amdgcn_mfma_f32_16x16x32_bf16(aA[i], bB[j], acc[i][j], 0, 0, 0);
        asm volatile("s_barrier" ::: "memory");
    }

    // ---- pixel-norm epilogue: this wave's 64 cols = one head of q/k/v
    const int colbase = bn0 + wc * 64;
    const int which = colbase >> 10;          // 0=q 1=k 2=v
    const int h = (colbase >> 6) & 15;
    float sc[4][4];
    #pragma unroll
    for (int i = 0; i < 4; i++)
        #pragma unroll
        for (int r = 0; r < 4; r++) {
            float ss = 0.f;
            #pragma unroll
            for (int j = 0; j < 4; j++) ss += acc[i][j][r] * acc[i][j][r];
            ss += __shfl_xor(ss, 1); ss += __shfl_xor(ss, 2);
            ss += __shfl_xor(ss, 4); ss += __shfl_xor(ss, 8);
            const float num = (which == 0) ? LOG2E : 8.0f;
            sc[i][r] = num / fmaxf(sqrtf(ss), EPSN);
        }
    if (which == 2) {
        #pragma unroll
        for (int i = 0; i < 4; i++) {
            const int row0 = bm0 + wr * 64 + i * 16 + quad * 4;
            const int bh = (row0 >> 11) * 16 + h;
            const int tok0 = row0 & 2047;
            #pragma unroll
            for (int j = 0; j < 4; j++) {
                const int d = j * 16 + l16;
                short4v o = {f2bf(acc[i][j][0] * sc[i][0]), f2bf(acc[i][j][1] * sc[i][1]),
                             f2bf(acc[i][j][2] * sc[i][2]), f2bf(acc[i][j][3] * sc[i][3])};
                *(short4v*)(Vt + ((size_t)bh * 64 + d) * NKEY + 4 + tok0) = o;
            }
        }
    } else {
        #pragma unroll
        for (int i = 0; i < 4; i++)
            #pragma unroll
            for (int r = 0; r < 4; r++) {
                const int row = bm0 + wr * 64 + i * 16 + quad * 4 + r;
                const int bh = (row >> 11) * 16 + h;
                const int tok = row & 2047;
                const size_t base = (which == 0) ? ((size_t)bh * 2048 + tok) * 64
                                                 : ((size_t)bh * NKEY + 4 + tok) * 64;
                short* dst = (which == 0) ? Qb : Kb;
                #pragma unroll
                for (int j = 0; j < 4; j++)
                    dst[base + j * 16 + l16] = f2bf(acc[i][j][r] * sc[i][r]);
            }
    }
}

// out-projection GEMM, pipelined, fp32 out + MP residual.
template<int MT, int NT>
__global__ __launch_bounds__(256) void gemm_mfma(const short* __restrict__ A,
                                                 const short* __restrict__ B,
                                                 float* __restrict__ C,
                                                 int M, int N, int K,
                                                 const float* __restrict__ resid) {
    constexpr int FI = MT / 32;
    constexpr int FJ = NT / 32;
    constexpr int nA = MT / 64;
    constexpr int nB = NT / 64;
    __shared__ __align__(16) short As[2][MT * 32];
    __shared__ __align__(16) short Bs[2][NT * 32];
    const int tid = threadIdx.x;
    const int wv = tid >> 6, lane = tid & 63;
    const int l16 = lane & 15, quad = lane >> 4;
    const int wr = wv >> 1, wc = wv & 1;
    const int bm0 = blockIdx.y * MT, bn0 = blockIdx.x * NT;
    const int grow = lane >> 2;
    const int gk = (lane & 3) * 8;

    floatx4 acc[FI][FJ];
    #pragma unroll
    for (int i = 0; i < FI; i++)
        #pragma unroll
        for (int j = 0; j < FJ; j++) acc[i][j] = (floatx4){0.f, 0.f, 0.f, 0.f};

    const short* Abase = A + (size_t)(bm0 + wv * (MT / 4) + grow) * K + gk;
    const short* Bbase = B + (size_t)(bn0 + wv * (NT / 4) + grow) * K + gk;

    #pragma unroll
    for (int j = 0; j < nA; j++)
        async16(&As[0][(wv * (MT / 4) + j * 16) * 32], Abase + (size_t)(j * 16) * K);
    #pragma unroll
    for (int j = 0; j < nB; j++)
        async16(&Bs[0][(wv * (NT / 4) + j * 16) * 32], Bbase + (size_t)(j * 16) * K);

    const int NKI = K >> 5;
    for (int ki = 0; ki < NKI; ki++) {
        const int cur = ki & 1;
        if (ki + 1 < NKI) {
            const int nxt = cur ^ 1;
            const int off = (ki + 1) * 32;
            #pragma unroll
            for (int j = 0; j < nA; j++)
                async16(&As[nxt][(wv * (MT / 4) + j * 16) * 32], Abase + (size_t)(j * 16) * K + off);
            #pragma unroll
            for (int j = 0; j < nB; j++)
                async16(&Bs[nxt][(wv * (NT / 4) + j * 16) * 32], Bbase + (size_t)(j * 16) * K + off);
            if constexpr (nA + nB == 4)      asm volatile("s_waitcnt vmcnt(4)" ::: "memory");
            else if constexpr (nA + nB == 3) asm volatile("s_waitcnt vmcnt(3)" ::: "memory");
            else                             asm volatile("s_waitcnt vmcnt(2)" ::: "memory");
        } else {
            asm volatile("s_waitcnt vmcnt(0)" ::: "memory");
        }
        asm volatile("s_barrier" ::: "memory");
        short8 aA[FI], bB[FJ];
        #pragma unroll
        for (int i = 0; i < FI; i++)
            aA[i] = *(const short8*)&As[cur][(wr * (MT / 2) + i * 16 + l16) * 32 + quad * 8];
        #pragma unroll
        for (int j = 0; j < FJ; j++)
            bB[j] = *(const short8*)&Bs[cur][(wc * (NT / 2) + j * 16 + l16) * 32 + quad * 8];
        #pragma unroll
        for (int i = 0; i < FI; i++)
            #pragma unroll
            for (int j = 0; j < FJ; j++)
                acc[i][j] = __builtin_amdgcn_mfma_f32_16x16x32_bf16(aA[i], bB[j], acc[i][j], 0, 0, 0);
        asm volatile("s_barrier" ::: "memory");
    }
    #pragma unroll
    for (int i = 0; i < FI; i++)
        #pragma unroll
        for (int j = 0; j < FJ; j++)
            #pragma unroll
            for (int r = 0; r < 4; r++) {
                const int row = bm0 + wr * (MT / 2) + i * 16 + quad * 4 + r;
                const int col = bn0 + wc * (NT / 2) + j * 16 + l16;
                const size_t idx = (size_t)row * N + col;
                float v = acc[i][j][r];
                if (resid) v = (v * 0.7f + resid[idx] * 0.3f) * 1.3130643285972254f;
                C[idx] = v;
            }
}

// Flash attention, transposed schedule. 256 thr = 4 waves x 32 q-rows.
// S^T = K·Q^T (A=K frag [key][d], B=Q frag [q][d]) -> C[key][q].
// P^T spilled to wave-private LDS in [q][key] B-layout (8 b64 writes, 4 b128
// reads, no barrier). O^T = V^T·P^T (A=V^T frag [d][key]). Fixed-shift exp2.
__global__ __launch_bounds__(256) void attn_mfma(const short* __restrict__ Qb,
                                                 const short* __restrict__ Kb,
                                                 const short* __restrict__ Vt,
                                                 short* __restrict__ out) {
    const int bh = blockIdx.x;
    const int q0 = blockIdx.y * 128;
    const int tid = threadIdx.x;
    const int wave = tid >> 6, lane = tid & 63;
    const int l16 = lane & 15, quad = lane >> 4;

    __shared__ __align__(16) short Ks2[2][2][64 * 32];  // [buf][d-half][key][32]
    __shared__ __align__(16) short Vs2[2][2][64 * 32];  // [buf][key-half][d][32]
    __shared__ __align__(16) short Pw[4][32 * 72];      // per-wave P^T [q][key]

    // Q B-fragments: rows q0 + wave*32 + qg*16 + l16, k-halves
    const short* qbase = Qb + ((size_t)bh * 2048 + q0 + wave * 32 + l16) * 64;
    short8 bQ[2][2];
    #pragma unroll
    for (int qg = 0; qg < 2; qg++)
        #pragma unroll
        for (int dh = 0; dh < 2; dh++)
            bQ[qg][dh] = *(const short8*)(qbase + qg * 1024 + dh * 32 + quad * 8);
    asm volatile("s_waitcnt vmcnt(0)" ::: "memory");   // Q resident before pipeline

    const int grow = lane >> 2, gsub = (lane & 3) * 8;
    auto issue = [&](int tile, int buf) {
        #pragma unroll
        for (int s = 0; s < 4; s++) {
            const int u = wave * 4 + s;        // wave-uniform
            if (u < 8) {
                const int dh = u >> 2, kc = u & 3;
                async16(&Ks2[buf][dh][kc * 512],
                        Kb + ((size_t)bh * NKEY + tile * 64 + kc * 16 + grow) * 64 + dh * 32 + gsub);
            } else {
                const int v = u - 8;
                const int kh = v >> 2, dc = v & 3;
                async16(&Vs2[buf][kh][dc * 512],
                        Vt + ((size_t)bh * 64 + dc * 16 + grow) * NKEY + tile * 64 + kh * 32 + gsub);
            }
        }
    };

    floatx4 O[4][2];   // [d-tile][q-group]
    #pragma unroll
    for (int dt = 0; dt < 4; dt++)
        #pragma unroll
        for (int qg = 0; qg < 2; qg++) O[dt][qg] = (floatx4){0.f, 0.f, 0.f, 0.f};
    float lp[2] = {0.f, 0.f};

    issue(0, 0);
    for (int tile = 0; tile < 33; tile++) {
        const int cur = tile & 1;
        if (tile < 32) {
            issue(tile + 1, cur ^ 1);
            asm volatile("s_waitcnt vmcnt(4)" ::: "memory");
        } else {
            asm volatile("s_waitcnt vmcnt(0)" ::: "memory");
        }
        asm volatile("s_barrier" ::: "memory");

        // ---- S^T = K·Q^T : C[key=quad*4+r][q=l16] per (kt, qg)
        floatx4 S[4][2];
        #pragma unroll
        for (int kt = 0; kt < 4; kt++) {
            short8 aK0 = *(const short8*)&Ks2[cur][0][(kt * 16 + l16) * 32 + quad * 8];
            short8 aK1 = *(const short8*)&Ks2[cur][1][(kt * 16 + l16) * 32 + quad * 8];
            #pragma unroll
            for (int qg = 0; qg < 2; qg++) {
                floatx4 s = (floatx4){-12.f, -12.f, -12.f, -12.f};
                s = __builtin_amdgcn_mfma_f32_16x16x32_bf16(aK0, bQ[qg][0], s, 0, 0, 0);
                s = __builtin_amdgcn_mfma_f32_16x16x32_bf16(aK1, bQ[qg][1], s, 0, 0, 0);
                S[kt][qg] = s;
            }
        }
        if (tile == 32) {   // valid keys: key_local < 4  <=>  kt==0 && quad==0
            #pragma unroll
            for (int kt = 0; kt < 4; kt++)
                #pragma unroll
                for (int qg = 0; qg < 2; qg++)
                    if (kt > 0 || quad > 0)
                        S[kt][qg] = (floatx4){-1e30f, -1e30f, -1e30f, -1e30f};
        }
        // ---- exp2, accumulate denominator, spill P^T in B-layout
        #pragma unroll
        for (int kt = 0; kt < 4; kt++)
            #pragma unroll
            for (int qg = 0; qg < 2; qg++) {
                float p0 = __builtin_amdgcn_exp2f(S[kt][qg][0]);
                float p1 = __builtin_amdgcn_exp2f(S[kt][qg][1]);
                float p2 = __builtin_amdgcn_exp2f(S[kt][qg][2]);
                float p3 = __builtin_amdgcn_exp2f(S[kt][qg][3]);
                lp[qg] += (p0 + p1) + (p2 + p3);
                short4v pk = {f2bf_fast(p0), f2bf_fast(p1), f2bf_fast(p2), f2bf_fast(p3)};
                *(short4v*)&Pw[wave][(qg * 16 + l16) * 72 + kt * 16 + quad * 4] = pk;
            }
        // ---- O^T += V^T·P^T
        short8 bP[2][2];
        #pragma unroll
        for (int qg = 0; qg < 2; qg++)
            #pragma unroll
            for (int kh = 0; kh < 2; kh++)
                bP[qg][kh] = *(const short8*)&Pw[wave][(qg * 16 + l16) * 72 + kh * 32 + quad * 8];
        #pragma unroll
        for (int dt = 0; dt < 4; dt++) {
            short8 aV0 = *(const short8*)&Vs2[cur][0][(dt * 16 + l16) * 32 + quad * 8];
            short8 aV1 = *(const short8*)&Vs2[cur][1][(dt * 16 + l16) * 32 + quad * 8];
            #pragma unroll
            for (int qg = 0; qg < 2; qg++) {
                O[dt][qg] = __builtin_amdgcn_mfma_f32_16x16x32_bf16(aV0, bP[qg][0], O[dt][qg], 0, 0, 0);
                O[dt][qg] = __builtin_amdgcn_mfma_f32_16x16x32_bf16(aV1, bP[qg][1], O[dt][qg], 0, 0, 0);
            }
        }
        asm volatile("s_barrier" ::: "memory");
    }

    // ---- epilogue: reduce denominator across quads, scale, store transposed
    const int bb = bh >> 4, h = bh & 15;
    float inv[2];
    #pragma unroll
    for (int qg = 0; qg < 2; qg++) {
        float l = lp[qg];
        l += __shfl_xor(l, 16);
        l += __shfl_xor(l, 32);
        inv[qg] = 1.0f / l;
    }
    #pragma unroll
    for (int dt = 0; dt < 4; dt++)
        #pragma unroll
        for (int qg = 0; qg < 2; qg++) {
            const int token = q0 + wave * 32 + qg * 16 + l16;
            short4v o = {f2bf(O[dt][qg][0] * inv[qg]), f2bf(O[dt][qg][1] * inv[qg]),
                         f2bf(O[dt][qg][2] * inv[qg]), f2bf(O[dt][qg][3] * inv[qg])};
            *(short4v*)(out + ((size_t)(bb * 2048 + token)) * 1024 + h * 64 + dt * 16 + quad * 4) = o;
        }
}

extern "C" void kernel_launch(void* const* d_in, const int* in_sizes, int n_in,
                              void* d_out, int out_size, void* d_ws, size_t ws_size,
                              hipStream_t stream) {
    const float* x      = (const float*)d_in[0];
    const float* w_qkv  = (const float*)d_in[1];
    const float* w_out  = (const float*)d_in[2];
    const float* mem_kv = (const float*)d_in[3];
    float* out = (float*)d_out;

    char* ws = (char*)d_ws;
    short* wnqkv_b = (short*)(ws);                    // 6 MB
    short* wnout_b = (short*)(ws + (6u << 20));       // 2 MB
    short* xb      = (short*)(ws + (8u << 20));       // 8 MB
    short* Qb      = (short*)(ws + (16u << 20));      // 8 MB
    short* Kb      = (short*)(ws + (24u << 20));      // 8.25 MB
    short* Vt      = (short*)(ws + (33u << 20));      // 8.25 MB
    short* attnb   = (short*)(ws + (42u << 20));      // 8 MB  (total ~50 MB)

    prep_inputs<<<8224, 256, 0, stream>>>(x, w_qkv, w_out, mem_kv,
                                          xb, wnqkv_b, wnout_b, Kb, Vt);

    gemm_qkv<<<dim3(3072 / 128, 4096 / 128), 256, 0, stream>>>(
        xb, wnqkv_b, Qb, Kb, Vt);

    attn_mfma<<<dim3(32, 16), 256, 0, stream>>>(Qb, Kb, Vt, attnb);

    gemm_mfma<128, 64><<<dim3(1024 / 64, 4096 / 128), 256, 0, stream>>>(
        attnb, wnout_b, out, 4096, 1024, 1024, x);
}